// Round 9
// baseline (362.610 us; speedup 1.0000x reference)
//
#include <hip/hip_runtime.h>

#define N_ATOMS   50000
#define N_EDGES   1600000
#define N_ANGLES  1500000
#define SCAN_B    196            // ceil(N_ATOMS/256)

// theta-table: theta = 8*sinh(u), u uniform on [-UMAX, UMAX], NT points.
#define NT      512
#define UMAX    4.852092f
#define H_U     0.01899253f      // 2*UMAX/(NT-1)
#define INV_HU  52.65766f        // (NT-1)/(2*UMAX)

typedef unsigned short u16;
typedef unsigned char  u8;
typedef _Float16 f16x8 __attribute__((ext_vector_type(8)));
typedef _Float16 f16x4 __attribute__((ext_vector_type(4)));
typedef float    f32x4 __attribute__((ext_vector_type(4)));
typedef u16      u16x8 __attribute__((ext_vector_type(8)));

__device__ __forceinline__ float silu_f(float x) {
    return __fdividef(x, 1.0f + __expf(-x));
}
__device__ __forceinline__ u16 f2h(float x) {
    _Float16 h = (_Float16)x;
    return __builtin_bit_cast(u16, h);
}
__device__ __forceinline__ float h2f(u16 u) {
    return (float)__builtin_bit_cast(_Float16, u);
}

// ---------------------------------------------------------------------------
// Edge precompute: EC8[e] = f16x4 (s/d, s/d^2*vec)  (8B record, halves the
// random-gather footprint vs 16B); spec8[e] = species[edge_dst[e]] (1.6 MB,
// L2-resident).
// ---------------------------------------------------------------------------
__global__ __launch_bounds__(256) void edge_kernel(
    const float* __restrict__ distances, const float* __restrict__ sw,
    const float* __restrict__ vec, const int* __restrict__ edge_dst,
    const int* __restrict__ species,
    float2* __restrict__ EC8, u8* __restrict__ spec8)
{
    int e = (int)blockIdx.x * 256 + (int)threadIdx.x;
    if (e >= N_EDGES) return;
    const float d   = distances[e];
    const float s   = sw[e];
    const float inv = 1.0f / d;
    const float sij = s * inv;
    const float c   = sij * inv;
    f16x4 h;
    h[0] = (_Float16)sij;
    h[1] = (_Float16)(c * vec[3*e+0]);
    h[2] = (_Float16)(c * vec[3*e+1]);
    h[3] = (_Float16)(c * vec[3*e+2]);
    EC8[e]   = __builtin_bit_cast(float2, h);
    spec8[e] = (u8)species[edge_dst[e]];
}

// ---------------------------------------------------------------------------
// Prep: WTl[n][k] = f16(Wl[k][n]);  base_tab[s*16+d][j] = W0[1+s][j]+W0[17+d][j]+b0[j]
// ---------------------------------------------------------------------------
__global__ __launch_bounds__(256) void prep_kernel(
    const float* __restrict__ W0, const float* __restrict__ b0,
    const float* __restrict__ W1, const float* __restrict__ W2,
    const float* __restrict__ W3,
    u16* __restrict__ WT1, u16* __restrict__ WT2, u16* __restrict__ WT3,
    float* __restrict__ base_tab)
{
    int t = (int)blockIdx.x * 256 + (int)threadIdx.x;
    if (t < 3 * 4096) {
        int l = t >> 12, e = t & 4095, n = e >> 6, k = e & 63;
        const float* W = (l == 0) ? W1 : (l == 1) ? W2 : W3;
        u16* WT        = (l == 0) ? WT1 : (l == 1) ? WT2 : WT3;
        WT[n*64 + k] = f2h(W[k*64 + n]);
    }
    int u = t - 3 * 4096;
    if (u >= 0 && u < 256 * 64) {
        int sd = u >> 6, j = u & 63, s = sd >> 4, d = sd & 15;
        base_tab[u] = W0[(1+s)*64 + j] + W0[(17+d)*64 + j] + b0[j];
    }
}

// ---------------------------------------------------------------------------
// CSR build: histogram -> 3-stage parallel scan -> gather+scatter
// ---------------------------------------------------------------------------
__global__ __launch_bounds__(256) void hist_kernel(
    const int* __restrict__ a_ca, int* __restrict__ cnt)
{
    int i = (int)blockIdx.x * 256 + (int)threadIdx.x;
    if (i < N_ANGLES) atomicAdd(&cnt[a_ca[i]], 1);
}

__global__ __launch_bounds__(256) void scanA_kernel(
    const int* __restrict__ cnt, int* __restrict__ bsum)
{
    __shared__ int ws[4];
    const int t = (int)threadIdx.x;
    const int idx = (int)blockIdx.x * 256 + t;
    int v = (idx < N_ATOMS) ? cnt[idx] : 0;
    #pragma unroll
    for (int off = 32; off; off >>= 1) v += __shfl_down(v, off, 64);
    if ((t & 63) == 0) ws[t >> 6] = v;
    __syncthreads();
    if (t == 0) bsum[blockIdx.x] = ws[0] + ws[1] + ws[2] + ws[3];
}

__global__ __launch_bounds__(256) void scanB_kernel(
    const int* __restrict__ bsum, int* __restrict__ boff)
{
    __shared__ int sh[256];
    const int t = (int)threadIdx.x;
    int v = (t < SCAN_B) ? bsum[t] : 0;
    sh[t] = v;
    __syncthreads();
    for (int off = 1; off < 256; off <<= 1) {
        int u = (t >= off) ? sh[t - off] : 0;
        __syncthreads();
        sh[t] += u;
        __syncthreads();
    }
    if (t < SCAN_B) boff[t] = sh[t] - v;   // exclusive
}

__global__ __launch_bounds__(256) void scanC_kernel(
    const int* __restrict__ cnt, const int* __restrict__ boff,
    int* __restrict__ cursor)
{
    __shared__ int sh[256];
    const int t = (int)threadIdx.x;
    const int idx = (int)blockIdx.x * 256 + t;
    int v = (idx < N_ATOMS) ? cnt[idx] : 0;
    sh[t] = v;
    __syncthreads();
    for (int off = 1; off < 256; off <<= 1) {
        int u = (t >= off) ? sh[t - off] : 0;
        __syncthreads();
        sh[t] += u;
        __syncthreads();
    }
    if (idx < N_ATOMS) cursor[idx] = boff[blockIdx.x] + sh[t] - v;
}

// Writes atom-sorted 8B record per angle: {theta, (pid<<17)|ca}.
// tri id (s<=d canonical, G symmetric in (s,d)): pid = 16s - s(s-1)/2 + (d-s).
// After this kernel, cursor[a] == CSR row-END of atom a (exploited by lookup).
__global__ __launch_bounds__(256) void scatter_kernel(
    const int* __restrict__ a_src, const int* __restrict__ a_dst,
    const int* __restrict__ a_ca, const float2* __restrict__ EC8,
    const u8* __restrict__ spec8,
    int* __restrict__ cursor, float2* __restrict__ rec)
{
    int i = (int)blockIdx.x * 256 + (int)threadIdx.x;
    if (i >= N_ANGLES) return;
    const int se = a_src[i], de = a_dst[i], ca = a_ca[i];
    const f16x4 rs = __builtin_bit_cast(f16x4, EC8[se]);
    const f16x4 rd = __builtin_bit_cast(f16x4, EC8[de]);
    const float theta = (float)rs[0]*(float)rd[0] + (float)rs[1]*(float)rd[1]
                      + (float)rs[2]*(float)rd[2] + (float)rs[3]*(float)rd[3];
    const int s1 = spec8[se], s2 = spec8[de];
    const int s = min(s1, s2), d = max(s1, s2);
    const int pid = s*16 - (s*(s-1))/2 + (d - s);
    const int pos = atomicAdd(&cursor[ca], 1);
    rec[pos] = make_float2(theta, __uint_as_float(((unsigned)pid << 17) | (unsigned)ca));
}

// ---------------------------------------------------------------------------
// MFMA helpers (static indexing; LDS tile u16 index = row*64 + (col^((row&7)<<3)))
// ---------------------------------------------------------------------------
__device__ __forceinline__ void dense_mfma(const u16* __restrict__ strip,
    const u16* __restrict__ WT, int r15, int g4, f32x4 acc[4][4])
{
    #pragma unroll
    for (int kt = 0; kt < 2; ++kt) {
        f16x8 A[4], B[4];
        #pragma unroll
        for (int mt = 0; mt < 4; ++mt) {
            int row = mt*16 + r15;
            int col = (kt*32 + g4*8) ^ ((row & 7) << 3);
            A[mt] = *(const f16x8*)&strip[row*64 + col];
        }
        #pragma unroll
        for (int nt = 0; nt < 4; ++nt)
            B[nt] = *(const f16x8*)&WT[(nt*16 + r15)*64 + kt*32 + g4*8];
        #pragma unroll
        for (int mt = 0; mt < 4; ++mt) {
            #pragma unroll
            for (int nt = 0; nt < 4; ++nt)
                acc[mt][nt] = __builtin_amdgcn_mfma_f32_16x16x32_f16(
                    A[mt], B[nt], acc[mt][nt], 0, 0, 0);
        }
    }
}

__device__ __forceinline__ void act_store(u16* __restrict__ strip,
    const float* __restrict__ bias, int r15, int g4, f32x4 acc[4][4])
{
    float bn[4];
    #pragma unroll
    for (int nt = 0; nt < 4; ++nt) bn[nt] = bias[nt*16 + r15];
    #pragma unroll
    for (int mt = 0; mt < 4; ++mt) {
        #pragma unroll
        for (int r = 0; r < 4; ++r) {
            int row = mt*16 + g4*4 + r;
            int rsw = (row & 7) << 3;
            #pragma unroll
            for (int nt = 0; nt < 4; ++nt)
                strip[row*64 + ((nt*16 + r15) ^ rsw)] =
                    f2h(silu_f(acc[mt][nt][r] + bn[nt]));
        }
    }
}

// ---------------------------------------------------------------------------
// Table build: grid = 136 pairs x 2 theta-chunks. Block = 4 waves x 64 rows.
// Row idx = chunk*256 + tid; theta = 8*sinh(-UMAX + idx*H_U).
// Writes G (NOT *theta) as f16: T[pid][idx][0:64].
// ---------------------------------------------------------------------------
__global__ __launch_bounds__(256) void build_kernel(
    const float* __restrict__ W0, const float* __restrict__ base_tab,
    const u16* __restrict__ WT1, const u16* __restrict__ WT2,
    const u16* __restrict__ WT3,
    const float* __restrict__ b1, const float* __restrict__ b2,
    const float* __restrict__ b3,
    u16* __restrict__ T)
{
    __shared__ __align__(16) u16 act[256 * 64];   // 32 KB

    const int tid  = (int)threadIdx.x;
    const int lane = tid & 63;
    const int wv   = tid >> 6;
    const int r15  = lane & 15;
    const int g4   = lane >> 4;

    const int pid   = (int)blockIdx.x >> 1;
    const int chunk = (int)blockIdx.x & 1;
    // decode tri id -> (s, d), s <= d
    int s = 0, rem = pid;
    while (rem >= 16 - s) { rem -= 16 - s; ++s; }
    const int d = s + rem;

    const int idx = chunk * 256 + tid;              // theta grid index
    const float u  = fmaf((float)idx, H_U, -UMAX);
    const float eu = __expf(u);
    const float theta = 4.0f * (eu - __frcp_rn(eu)); // 8*sinh(u)

    u16* strip = act + wv * 4096;

    f32x4 accG[4][4];
    #pragma unroll
    for (int nt = 0; nt < 4; ++nt) {
        float bv = 2.0f * b3[nt*16 + r15];
        #pragma unroll
        for (int mt = 0; mt < 4; ++mt) accG[mt][nt] = {bv, bv, bv, bv};
    }

    #pragma unroll 1
    for (int m = 0; m < 2; ++m) {
        // layer 0 (one-hot collapsed)
        {
            const int p = m ? (d*16 + s) : (s*16 + d);
            const float4* bs4 = (const float4*)(base_tab + p*64);
            const float4* w04 = (const float4*)W0;
            const int rsw = (lane & 7) << 3;
            #pragma unroll
            for (int c = 0; c < 8; ++c) {
                float4 bl = bs4[2*c], bh = bs4[2*c+1];
                float4 wl = w04[2*c], wh = w04[2*c+1];
                u16x8 hv;
                hv[0] = f2h(silu_f(fmaf(theta, wl.x, bl.x)));
                hv[1] = f2h(silu_f(fmaf(theta, wl.y, bl.y)));
                hv[2] = f2h(silu_f(fmaf(theta, wl.z, bl.z)));
                hv[3] = f2h(silu_f(fmaf(theta, wl.w, bl.w)));
                hv[4] = f2h(silu_f(fmaf(theta, wh.x, bh.x)));
                hv[5] = f2h(silu_f(fmaf(theta, wh.y, bh.y)));
                hv[6] = f2h(silu_f(fmaf(theta, wh.z, bh.z)));
                hv[7] = f2h(silu_f(fmaf(theta, wh.w, bh.w)));
                *(u16x8*)&strip[lane*64 + ((c*8) ^ rsw)] = hv;
            }
        }
        // layer 1
        {
            f32x4 acc[4][4];
            #pragma unroll
            for (int mt = 0; mt < 4; ++mt)
                #pragma unroll
                for (int nt = 0; nt < 4; ++nt) acc[mt][nt] = {0.f,0.f,0.f,0.f};
            dense_mfma(strip, WT1, r15, g4, acc);
            act_store(strip, b1, r15, g4, acc);
        }
        // layer 2
        {
            f32x4 acc[4][4];
            #pragma unroll
            for (int mt = 0; mt < 4; ++mt)
                #pragma unroll
                for (int nt = 0; nt < 4; ++nt) acc[mt][nt] = {0.f,0.f,0.f,0.f};
            dense_mfma(strip, WT2, r15, g4, acc);
            act_store(strip, b2, r15, g4, acc);
        }
        // layer 3 -> persistent accG
        dense_mfma(strip, WT3, r15, g4, accG);
    }

    // stash G (f16) into act rows
    #pragma unroll
    for (int mt = 0; mt < 4; ++mt) {
        #pragma unroll
        for (int r = 0; r < 4; ++r) {
            int row = mt*16 + g4*4 + r;
            int rsw = (row & 7) << 3;
            #pragma unroll
            for (int nt = 0; nt < 4; ++nt)
                strip[row*64 + ((nt*16 + r15) ^ rsw)] = f2h(accG[mt][nt][r]);
        }
    }
    __syncthreads();

    // coalesced copy-out: thread tid owns act row tid -> T[pid][idx]
    u16* dst = T + ((size_t)pid * NT + (size_t)idx) * 64;
    const int rsw = (tid & 7) << 3;
    #pragma unroll
    for (int c = 0; c < 8; ++c)
        *(u16x8*)(dst + c*8) = *(const u16x8*)&act[tid*64 + ((c*8) ^ rsw)];
}

// ---------------------------------------------------------------------------
// Lookup: wave-per-atom CSR walk, lane = feature. Per angle: uniform record
// read + index math (shared by all lanes), two coalesced 128B table-row reads,
// lerp, f32 register accumulate. One coalesced direct STORE per atom — no LDS,
// no atomics, no out-memset (every atom row written exactly once).
// post-scatter cursor[a] == row END of atom a; start = a ? cursor[a-1] : 0.
// ---------------------------------------------------------------------------
__global__ __launch_bounds__(256) void lookup_kernel(
    const float2* __restrict__ rec, const int* __restrict__ cursor,
    const u16* __restrict__ T, float* __restrict__ out)
{
    const int tid  = (int)threadIdx.x;
    const int lane = tid & 63;
    const int wv   = tid >> 6;
    const int atom = (int)blockIdx.x * 4 + wv;
    if (atom >= N_ATOMS) return;

    const int start = atom ? cursor[atom - 1] : 0;
    const int end   = cursor[atom];

    float acc = 0.0f;
    for (int i = start; i < end; ++i) {
        const float2 rv = rec[i];
        const float theta = rv.x;
        const int pid = (int)(__float_as_uint(rv.y) >> 17);

        // u = asinh(theta/8); tt = (u+UMAX)/h_u; lerp rows i0, i0+1
        const float x  = theta * 0.125f;
        const float ax = fabsf(x);
        float uu = __logf(ax + __fsqrt_rn(fmaf(ax, ax, 1.0f)));
        uu = copysignf(uu, x);
        float tt = fminf(fmaxf(fmaf(uu, INV_HU, UMAX * INV_HU), 0.0f),
                         (float)NT - 1.001f);
        const int   i0 = (int)tt;
        const float fr = tt - (float)i0;

        const u16* __restrict__ r0 = T + ((size_t)pid * NT + (size_t)i0) * 64;
        const float ga = h2f(r0[lane]);
        const float gb = h2f(r0[64 + lane]);
        acc = fmaf(fmaf(fr, gb - ga, ga), theta, acc);
    }
    out[(size_t)atom * 64 + lane] = acc;
}

extern "C" void kernel_launch(void* const* d_in, const int* in_sizes, int n_in,
                              void* d_out, int out_size, void* d_ws, size_t ws_size,
                              hipStream_t stream) {
    const int*   species   = (const int*)  d_in[0];
    const int*   edge_dst  = (const int*)  d_in[1];
    const float* distances = (const float*)d_in[2];
    const float* sw        = (const float*)d_in[3];
    const float* vec       = (const float*)d_in[4];
    const int*   a_src     = (const int*)  d_in[5];
    const int*   a_dst     = (const int*)  d_in[6];
    const int*   a_ca      = (const int*)  d_in[7];
    const float* W0 = (const float*)d_in[8];
    const float* b0 = (const float*)d_in[9];
    const float* W1 = (const float*)d_in[10];
    const float* b1 = (const float*)d_in[11];
    const float* W2 = (const float*)d_in[12];
    const float* b2 = (const float*)d_in[13];
    const float* W3 = (const float*)d_in[14];
    const float* b3 = (const float*)d_in[15];
    float* out = (float*)d_out;

    // ws: EC8 12.8M | spec8 1.6M | cnt | cursor | bsum | boff | rec 12M |
    //     WT1/2/3 | base_tab | T 8.9M   (~36 MB; spec8 len 1.6e6 % 16 == 0,
    //     int prefix 100392*4 % 8 == 0 -> rec stays 8B-aligned)
    float2* EC8    = (float2*)d_ws;
    u8*     spec8  = (u8*)(EC8 + N_EDGES);
    int*    cnt    = (int*)(spec8 + N_EDGES);
    int*    cursor = cnt + N_ATOMS;
    int*    bsum   = cursor + N_ATOMS;
    int*    boff   = bsum + SCAN_B;
    float2* rec    = (float2*)(boff + SCAN_B);
    u16*    WT1    = (u16*)(rec + N_ANGLES);
    u16*    WT2    = WT1 + 4096;
    u16*    WT3    = WT2 + 4096;
    float*  base_tab = (float*)(WT3 + 4096);
    u16*    T      = (u16*)(base_tab + 256*64);

    hipMemsetAsync(cnt, 0, (size_t)N_ATOMS * sizeof(int), stream);

    edge_kernel<<<(N_EDGES + 255) / 256, 256, 0, stream>>>(
        distances, sw, vec, edge_dst, species, EC8, spec8);
    prep_kernel<<<(3*4096 + 256*64 + 255) / 256, 256, 0, stream>>>(
        W0, b0, W1, W2, W3, WT1, WT2, WT3, base_tab);
    hist_kernel<<<(N_ANGLES + 255) / 256, 256, 0, stream>>>(a_ca, cnt);
    scanA_kernel<<<SCAN_B, 256, 0, stream>>>(cnt, bsum);
    scanB_kernel<<<1, 256, 0, stream>>>(bsum, boff);
    scanC_kernel<<<SCAN_B, 256, 0, stream>>>(cnt, boff, cursor);
    scatter_kernel<<<(N_ANGLES + 255) / 256, 256, 0, stream>>>(
        a_src, a_dst, a_ca, EC8, spec8, cursor, rec);
    build_kernel<<<136 * 2, 256, 0, stream>>>(
        W0, base_tab, WT1, WT2, WT3, b1, b2, b3, T);
    lookup_kernel<<<(N_ATOMS + 3) / 4, 256, 0, stream>>>(rec, cursor, T, out);
}

// Round 10
// 313.884 us; speedup vs baseline: 1.1552x; 1.1552x over previous
//
#include <hip/hip_runtime.h>

#define N_ATOMS   50000
#define N_EDGES   1600000
#define N_ANGLES  1500000
#define SCAN_B    196            // ceil(N_ATOMS/256)

// theta-table: theta = 8*sinh(u), u uniform on [-UMAX, UMAX], NT points.
#define NT      512
#define UMAX    4.852092f
#define H_U     0.01899253f      // 2*UMAX/(NT-1)
#define INV_HU  52.65766f        // (NT-1)/(2*UMAX)

typedef unsigned short u16;
typedef unsigned char  u8;
typedef unsigned int   u32;
typedef _Float16 f16x8 __attribute__((ext_vector_type(8)));
typedef _Float16 f16x4 __attribute__((ext_vector_type(4)));
typedef float    f32x4 __attribute__((ext_vector_type(4)));
typedef u16      u16x8 __attribute__((ext_vector_type(8)));

__device__ __forceinline__ float silu_f(float x) {
    return __fdividef(x, 1.0f + __expf(-x));
}
__device__ __forceinline__ u16 f2h(float x) {
    _Float16 h = (_Float16)x;
    return __builtin_bit_cast(u16, h);
}
__device__ __forceinline__ float h2f(u16 u) {
    return (float)__builtin_bit_cast(_Float16, u);
}

// ---------------------------------------------------------------------------
// Edge precompute: EC8[e] = f16x4 (s/d, s/d^2*vec); spec8[e] = species[edge_dst]
// ---------------------------------------------------------------------------
__global__ __launch_bounds__(256) void edge_kernel(
    const float* __restrict__ distances, const float* __restrict__ sw,
    const float* __restrict__ vec, const int* __restrict__ edge_dst,
    const int* __restrict__ species,
    float2* __restrict__ EC8, u8* __restrict__ spec8)
{
    int e = (int)blockIdx.x * 256 + (int)threadIdx.x;
    if (e >= N_EDGES) return;
    const float d   = distances[e];
    const float s   = sw[e];
    const float inv = 1.0f / d;
    const float sij = s * inv;
    const float c   = sij * inv;
    f16x4 h;
    h[0] = (_Float16)sij;
    h[1] = (_Float16)(c * vec[3*e+0]);
    h[2] = (_Float16)(c * vec[3*e+1]);
    h[3] = (_Float16)(c * vec[3*e+2]);
    EC8[e]   = __builtin_bit_cast(float2, h);
    spec8[e] = (u8)species[edge_dst[e]];
}

// ---------------------------------------------------------------------------
// Prep: WTl[n][k] = f16(Wl[k][n]);  base_tab[s*16+d][j] = W0[1+s][j]+W0[17+d][j]+b0[j]
// ---------------------------------------------------------------------------
__global__ __launch_bounds__(256) void prep_kernel(
    const float* __restrict__ W0, const float* __restrict__ b0,
    const float* __restrict__ W1, const float* __restrict__ W2,
    const float* __restrict__ W3,
    u16* __restrict__ WT1, u16* __restrict__ WT2, u16* __restrict__ WT3,
    float* __restrict__ base_tab)
{
    int t = (int)blockIdx.x * 256 + (int)threadIdx.x;
    if (t < 3 * 4096) {
        int l = t >> 12, e = t & 4095, n = e >> 6, k = e & 63;
        const float* W = (l == 0) ? W1 : (l == 1) ? W2 : W3;
        u16* WT        = (l == 0) ? WT1 : (l == 1) ? WT2 : WT3;
        WT[n*64 + k] = f2h(W[k*64 + n]);
    }
    int u = t - 3 * 4096;
    if (u >= 0 && u < 256 * 64) {
        int sd = u >> 6, j = u & 63, s = sd >> 4, d = sd & 15;
        base_tab[u] = W0[(1+s)*64 + j] + W0[(17+d)*64 + j] + b0[j];
    }
}

// ---------------------------------------------------------------------------
// CSR build: histogram -> 3-stage parallel scan -> gather+scatter
// ---------------------------------------------------------------------------
__global__ __launch_bounds__(256) void hist_kernel(
    const int* __restrict__ a_ca, int* __restrict__ cnt)
{
    int i = (int)blockIdx.x * 256 + (int)threadIdx.x;
    if (i < N_ANGLES) atomicAdd(&cnt[a_ca[i]], 1);
}

__global__ __launch_bounds__(256) void scanA_kernel(
    const int* __restrict__ cnt, int* __restrict__ bsum)
{
    __shared__ int ws[4];
    const int t = (int)threadIdx.x;
    const int idx = (int)blockIdx.x * 256 + t;
    int v = (idx < N_ATOMS) ? cnt[idx] : 0;
    #pragma unroll
    for (int off = 32; off; off >>= 1) v += __shfl_down(v, off, 64);
    if ((t & 63) == 0) ws[t >> 6] = v;
    __syncthreads();
    if (t == 0) bsum[blockIdx.x] = ws[0] + ws[1] + ws[2] + ws[3];
}

__global__ __launch_bounds__(256) void scanB_kernel(
    const int* __restrict__ bsum, int* __restrict__ boff)
{
    __shared__ int sh[256];
    const int t = (int)threadIdx.x;
    int v = (t < SCAN_B) ? bsum[t] : 0;
    sh[t] = v;
    __syncthreads();
    for (int off = 1; off < 256; off <<= 1) {
        int u = (t >= off) ? sh[t - off] : 0;
        __syncthreads();
        sh[t] += u;
        __syncthreads();
    }
    if (t < SCAN_B) boff[t] = sh[t] - v;   // exclusive
}

__global__ __launch_bounds__(256) void scanC_kernel(
    const int* __restrict__ cnt, const int* __restrict__ boff,
    int* __restrict__ cursor)
{
    __shared__ int sh[256];
    const int t = (int)threadIdx.x;
    const int idx = (int)blockIdx.x * 256 + t;
    int v = (idx < N_ATOMS) ? cnt[idx] : 0;
    sh[t] = v;
    __syncthreads();
    for (int off = 1; off < 256; off <<= 1) {
        int u = (t >= off) ? sh[t - off] : 0;
        __syncthreads();
        sh[t] += u;
        __syncthreads();
    }
    if (idx < N_ATOMS) cursor[idx] = boff[blockIdx.x] + sh[t] - v;
}

// Writes atom-sorted 8B record per angle: {f32 theta, (tt_fx<<8)|pid}.
// tt_fx = table coord in 9.15 fixed point (asinh chain computed HERE, where
// the kernel is gather-latency-bound with VALUBusy ~1% — transcendentals free).
// tri pid (s<=d canonical): pid = 16s - s(s-1)/2 + (d-s) < 136.
// After this kernel, cursor[a] == CSR row-END of atom a.
__global__ __launch_bounds__(256) void scatter_kernel(
    const int* __restrict__ a_src, const int* __restrict__ a_dst,
    const int* __restrict__ a_ca, const float2* __restrict__ EC8,
    const u8* __restrict__ spec8,
    int* __restrict__ cursor, float2* __restrict__ rec)
{
    int i = (int)blockIdx.x * 256 + (int)threadIdx.x;
    if (i >= N_ANGLES) return;
    const int se = a_src[i], de = a_dst[i], ca = a_ca[i];
    const f16x4 rs = __builtin_bit_cast(f16x4, EC8[se]);
    const f16x4 rd = __builtin_bit_cast(f16x4, EC8[de]);
    const float theta = (float)rs[0]*(float)rd[0] + (float)rs[1]*(float)rd[1]
                      + (float)rs[2]*(float)rd[2] + (float)rs[3]*(float)rd[3];
    const int s1 = spec8[se], s2 = spec8[de];
    const int s = min(s1, s2), d = max(s1, s2);
    const int pid = s*16 - (s*(s-1))/2 + (d - s);

    // u = asinh(theta/8); tt = (u+UMAX)/h_u in [0, NT-1.001]
    const float x  = theta * 0.125f;
    const float ax = fabsf(x);
    float uu = __logf(ax + __fsqrt_rn(fmaf(ax, ax, 1.0f)));
    uu = copysignf(uu, x);
    const float tt = fminf(fmaxf(fmaf(uu, INV_HU, UMAX * INV_HU), 0.0f),
                           (float)NT - 1.001f);
    const u32 tfx = (u32)(tt * 32768.0f);          // 9.15 fixed, < 2^24

    const int pos = atomicAdd(&cursor[ca], 1);
    rec[pos] = make_float2(theta, __uint_as_float((tfx << 8) | (u32)pid));
}

// ---------------------------------------------------------------------------
// MFMA helpers (static indexing; LDS tile u16 index = row*64 + (col^((row&7)<<3)))
// ---------------------------------------------------------------------------
__device__ __forceinline__ void dense_mfma(const u16* __restrict__ strip,
    const u16* __restrict__ WT, int r15, int g4, f32x4 acc[4][4])
{
    #pragma unroll
    for (int kt = 0; kt < 2; ++kt) {
        f16x8 A[4], B[4];
        #pragma unroll
        for (int mt = 0; mt < 4; ++mt) {
            int row = mt*16 + r15;
            int col = (kt*32 + g4*8) ^ ((row & 7) << 3);
            A[mt] = *(const f16x8*)&strip[row*64 + col];
        }
        #pragma unroll
        for (int nt = 0; nt < 4; ++nt)
            B[nt] = *(const f16x8*)&WT[(nt*16 + r15)*64 + kt*32 + g4*8];
        #pragma unroll
        for (int mt = 0; mt < 4; ++mt) {
            #pragma unroll
            for (int nt = 0; nt < 4; ++nt)
                acc[mt][nt] = __builtin_amdgcn_mfma_f32_16x16x32_f16(
                    A[mt], B[nt], acc[mt][nt], 0, 0, 0);
        }
    }
}

__device__ __forceinline__ void act_store(u16* __restrict__ strip,
    const float* __restrict__ bias, int r15, int g4, f32x4 acc[4][4])
{
    float bn[4];
    #pragma unroll
    for (int nt = 0; nt < 4; ++nt) bn[nt] = bias[nt*16 + r15];
    #pragma unroll
    for (int mt = 0; mt < 4; ++mt) {
        #pragma unroll
        for (int r = 0; r < 4; ++r) {
            int row = mt*16 + g4*4 + r;
            int rsw = (row & 7) << 3;
            #pragma unroll
            for (int nt = 0; nt < 4; ++nt)
                strip[row*64 + ((nt*16 + r15) ^ rsw)] =
                    f2h(silu_f(acc[mt][nt][r] + bn[nt]));
        }
    }
}

// ---------------------------------------------------------------------------
// Table build: grid = 136 pairs x 2 theta-chunks. Block = 4 waves x 64 rows.
// Writes G as f16: T[pid][idx][0:64].
// ---------------------------------------------------------------------------
__global__ __launch_bounds__(256) void build_kernel(
    const float* __restrict__ W0, const float* __restrict__ base_tab,
    const u16* __restrict__ WT1, const u16* __restrict__ WT2,
    const u16* __restrict__ WT3,
    const float* __restrict__ b1, const float* __restrict__ b2,
    const float* __restrict__ b3,
    u16* __restrict__ T)
{
    __shared__ __align__(16) u16 act[256 * 64];   // 32 KB

    const int tid  = (int)threadIdx.x;
    const int lane = tid & 63;
    const int wv   = tid >> 6;
    const int r15  = lane & 15;
    const int g4   = lane >> 4;

    const int pid   = (int)blockIdx.x >> 1;
    const int chunk = (int)blockIdx.x & 1;
    // decode tri id -> (s, d), s <= d
    int s = 0, rem = pid;
    while (rem >= 16 - s) { rem -= 16 - s; ++s; }
    const int d = s + rem;

    const int idx = chunk * 256 + tid;              // theta grid index
    const float u  = fmaf((float)idx, H_U, -UMAX);
    const float eu = __expf(u);
    const float theta = 4.0f * (eu - __frcp_rn(eu)); // 8*sinh(u)

    u16* strip = act + wv * 4096;

    f32x4 accG[4][4];
    #pragma unroll
    for (int nt = 0; nt < 4; ++nt) {
        float bv = 2.0f * b3[nt*16 + r15];
        #pragma unroll
        for (int mt = 0; mt < 4; ++mt) accG[mt][nt] = {bv, bv, bv, bv};
    }

    #pragma unroll 1
    for (int m = 0; m < 2; ++m) {
        // layer 0 (one-hot collapsed)
        {
            const int p = m ? (d*16 + s) : (s*16 + d);
            const float4* bs4 = (const float4*)(base_tab + p*64);
            const float4* w04 = (const float4*)W0;
            const int rsw = (lane & 7) << 3;
            #pragma unroll
            for (int c = 0; c < 8; ++c) {
                float4 bl = bs4[2*c], bh = bs4[2*c+1];
                float4 wl = w04[2*c], wh = w04[2*c+1];
                u16x8 hv;
                hv[0] = f2h(silu_f(fmaf(theta, wl.x, bl.x)));
                hv[1] = f2h(silu_f(fmaf(theta, wl.y, bl.y)));
                hv[2] = f2h(silu_f(fmaf(theta, wl.z, bl.z)));
                hv[3] = f2h(silu_f(fmaf(theta, wl.w, bl.w)));
                hv[4] = f2h(silu_f(fmaf(theta, wh.x, bh.x)));
                hv[5] = f2h(silu_f(fmaf(theta, wh.y, bh.y)));
                hv[6] = f2h(silu_f(fmaf(theta, wh.z, bh.z)));
                hv[7] = f2h(silu_f(fmaf(theta, wh.w, bh.w)));
                *(u16x8*)&strip[lane*64 + ((c*8) ^ rsw)] = hv;
            }
        }
        // layer 1
        {
            f32x4 acc[4][4];
            #pragma unroll
            for (int mt = 0; mt < 4; ++mt)
                #pragma unroll
                for (int nt = 0; nt < 4; ++nt) acc[mt][nt] = {0.f,0.f,0.f,0.f};
            dense_mfma(strip, WT1, r15, g4, acc);
            act_store(strip, b1, r15, g4, acc);
        }
        // layer 2
        {
            f32x4 acc[4][4];
            #pragma unroll
            for (int mt = 0; mt < 4; ++mt)
                #pragma unroll
                for (int nt = 0; nt < 4; ++nt) acc[mt][nt] = {0.f,0.f,0.f,0.f};
            dense_mfma(strip, WT2, r15, g4, acc);
            act_store(strip, b2, r15, g4, acc);
        }
        // layer 3 -> persistent accG
        dense_mfma(strip, WT3, r15, g4, accG);
    }

    // stash G (f16) into act rows
    #pragma unroll
    for (int mt = 0; mt < 4; ++mt) {
        #pragma unroll
        for (int r = 0; r < 4; ++r) {
            int row = mt*16 + g4*4 + r;
            int rsw = (row & 7) << 3;
            #pragma unroll
            for (int nt = 0; nt < 4; ++nt)
                strip[row*64 + ((nt*16 + r15) ^ rsw)] = f2h(accG[mt][nt][r]);
        }
    }
    __syncthreads();

    // coalesced copy-out: thread tid owns act row tid -> T[pid][idx]
    u16* dst = T + ((size_t)pid * NT + (size_t)idx) * 64;
    const int rsw = (tid & 7) << 3;
    #pragma unroll
    for (int c = 0; c < 8; ++c)
        *(u16x8*)(dst + c*8) = *(const u16x8*)&act[tid*64 + ((c*8) ^ rsw)];
}

// ---------------------------------------------------------------------------
// Repack: T2[pid][i][lane] = pack(T[pid][i][lane], T[pid][min(i+1,NT-1)][lane])
// -> lookup does ONE dword load per angle instead of two u16 row loads.
// ---------------------------------------------------------------------------
__global__ __launch_bounds__(256) void repack_kernel(
    const u16* __restrict__ T, u32* __restrict__ T2)
{
    int idx = (int)blockIdx.x * 256 + (int)threadIdx.x;
    if (idx >= 136 * NT * 64) return;
    const int row = (idx >> 6) & (NT - 1);
    const u16 a = T[idx];
    const u16 b = T[(row < NT - 1) ? idx + 64 : idx];
    T2[idx] = (u32)a | ((u32)b << 16);
}

// ---------------------------------------------------------------------------
// Lookup: wave-per-atom CSR walk, lane = feature. Per angle: uniform 8B record
// (scalarized via readfirstlane -> s_load + SALU unpack, dual-issues with VALU),
// one coalesced dword T2 load, lerp, f32 register accumulate. One direct store
// per atom row — no LDS, no atomics, no memset.
// ---------------------------------------------------------------------------
__global__ __launch_bounds__(256) void lookup_kernel(
    const float2* __restrict__ rec, const int* __restrict__ cursor,
    const u32* __restrict__ T2, float* __restrict__ out)
{
    const int tid  = (int)threadIdx.x;
    const int lane = tid & 63;
    const int wv   = tid >> 6;
    const int atom = (int)blockIdx.x * 4 + wv;
    if (atom >= N_ATOMS) return;

    const int start = atom ? cursor[atom - 1] : 0;
    const int end   = cursor[atom];

    float acc = 0.0f;
    for (int i = start; i < end; ++i) {
        const float2 rv = rec[__builtin_amdgcn_readfirstlane(i)];
        const float theta = rv.x;
        const u32 w   = __float_as_uint(rv.y);
        const u32 pid = w & 255u;
        const u32 tfx = w >> 8;
        const u32 i0  = tfx >> 15;
        const float fr = (float)(tfx & 32767u) * (1.0f / 32768.0f);
        const u32 off = (pid << 15) + (i0 << 6) + (u32)lane;  // pid*NT*64
        const u32 pr = T2[off];
        const float ga = h2f((u16)(pr & 0xFFFFu));
        const float gb = h2f((u16)(pr >> 16));
        acc = fmaf(fmaf(fr, gb - ga, ga), theta, acc);
    }
    out[(size_t)atom * 64 + lane] = acc;
}

extern "C" void kernel_launch(void* const* d_in, const int* in_sizes, int n_in,
                              void* d_out, int out_size, void* d_ws, size_t ws_size,
                              hipStream_t stream) {
    const int*   species   = (const int*)  d_in[0];
    const int*   edge_dst  = (const int*)  d_in[1];
    const float* distances = (const float*)d_in[2];
    const float* sw        = (const float*)d_in[3];
    const float* vec       = (const float*)d_in[4];
    const int*   a_src     = (const int*)  d_in[5];
    const int*   a_dst     = (const int*)  d_in[6];
    const int*   a_ca      = (const int*)  d_in[7];
    const float* W0 = (const float*)d_in[8];
    const float* b0 = (const float*)d_in[9];
    const float* W1 = (const float*)d_in[10];
    const float* b1 = (const float*)d_in[11];
    const float* W2 = (const float*)d_in[12];
    const float* b2 = (const float*)d_in[13];
    const float* W3 = (const float*)d_in[14];
    const float* b3 = (const float*)d_in[15];
    float* out = (float*)d_out;

    // ws: EC8 12.8M | spec8 1.6M | cnt | cursor | bsum | boff | rec 12M |
    //     WT1/2/3 | base_tab | T 8.9M | T2 17.8M   (~54 MB)
    float2* EC8    = (float2*)d_ws;
    u8*     spec8  = (u8*)(EC8 + N_EDGES);
    int*    cnt    = (int*)(spec8 + N_EDGES);
    int*    cursor = cnt + N_ATOMS;
    int*    bsum   = cursor + N_ATOMS;
    int*    boff   = bsum + SCAN_B;
    float2* rec    = (float2*)(boff + SCAN_B);
    u16*    WT1    = (u16*)(rec + N_ANGLES);
    u16*    WT2    = WT1 + 4096;
    u16*    WT3    = WT2 + 4096;
    float*  base_tab = (float*)(WT3 + 4096);
    u16*    T      = (u16*)(base_tab + 256*64);
    u32*    T2     = (u32*)(T + 136 * NT * 64);

    hipMemsetAsync(cnt, 0, (size_t)N_ATOMS * sizeof(int), stream);

    edge_kernel<<<(N_EDGES + 255) / 256, 256, 0, stream>>>(
        distances, sw, vec, edge_dst, species, EC8, spec8);
    prep_kernel<<<(3*4096 + 256*64 + 255) / 256, 256, 0, stream>>>(
        W0, b0, W1, W2, W3, WT1, WT2, WT3, base_tab);
    hist_kernel<<<(N_ANGLES + 255) / 256, 256, 0, stream>>>(a_ca, cnt);
    scanA_kernel<<<SCAN_B, 256, 0, stream>>>(cnt, bsum);
    scanB_kernel<<<1, 256, 0, stream>>>(bsum, boff);
    scanC_kernel<<<SCAN_B, 256, 0, stream>>>(cnt, boff, cursor);
    scatter_kernel<<<(N_ANGLES + 255) / 256, 256, 0, stream>>>(
        a_src, a_dst, a_ca, EC8, spec8, cursor, rec);
    build_kernel<<<136 * 2, 256, 0, stream>>>(
        W0, base_tab, WT1, WT2, WT3, b1, b2, b3, T);
    repack_kernel<<<(136 * NT * 64 + 255) / 256, 256, 0, stream>>>(T, T2);
    lookup_kernel<<<(N_ATOMS + 3) / 4, 256, 0, stream>>>(rec, cursor, T2, out);
}

// Round 11
// 274.931 us; speedup vs baseline: 1.3189x; 1.1417x over previous
//
#include <hip/hip_runtime.h>

#define N_ATOMS   50000
#define N_EDGES   1600000
#define N_ANGLES  1500000
#define SCAN_B    196            // ceil(N_ATOMS/256)

// theta-table: theta = 8*sinh(u), u uniform on [-UMAX, UMAX], NT points.
#define NT      256
#define UMAX    4.852092f
#define H_U     0.038055623f     // 2*UMAX/(NT-1)
#define INV_HU  26.277306f       // (NT-1)/(2*UMAX)
#define TSZ     (136 * NT * 64)  // one partial table

#define E_BLK   6250             // edge range blocks
#define P_BLK   112              // prep range blocks (3*4096+16384)/256
#define Z_BLK   196              // cnt-zero range blocks

typedef unsigned short u16;
typedef unsigned int   u32;
typedef _Float16 f16x8 __attribute__((ext_vector_type(8)));
typedef float    f32x4 __attribute__((ext_vector_type(4)));
typedef u16      u16x8 __attribute__((ext_vector_type(8)));

__device__ __forceinline__ float silu_f(float x) {
    return __fdividef(x, 1.0f + __expf(-x));
}
__device__ __forceinline__ u16 f2h(float x) {
    _Float16 h = (_Float16)x;
    return __builtin_bit_cast(u16, h);
}
__device__ __forceinline__ float h2f(u16 u) {
    return (float)__builtin_bit_cast(_Float16, u);
}

// ---------------------------------------------------------------------------
// Fused prep: [0,E_BLK) edge records (species embedded in f16 LSBs, 2^-11
// perturbation); [E_BLK,+P_BLK) weight transpose + base_tab; [+P_BLK,+Z_BLK)
// cnt zeroing (replaces hipMemsetAsync dispatch).
// ---------------------------------------------------------------------------
__global__ __launch_bounds__(256) void fused_prep_kernel(
    const float* __restrict__ distances, const float* __restrict__ sw,
    const float* __restrict__ vec, const int* __restrict__ edge_dst,
    const int* __restrict__ species,
    const float* __restrict__ W0, const float* __restrict__ b0,
    const float* __restrict__ W1, const float* __restrict__ W2,
    const float* __restrict__ W3,
    float2* __restrict__ EC8,
    u16* __restrict__ WT1, u16* __restrict__ WT2, u16* __restrict__ WT3,
    float* __restrict__ base_tab, int* __restrict__ cnt)
{
    const int bid = (int)blockIdx.x;
    const int tid = (int)threadIdx.x;

    if (bid < E_BLK) {
        int e = bid * 256 + tid;
        if (e >= N_EDGES) return;
        const float d   = distances[e];
        const float s   = sw[e];
        const float inv = 1.0f / d;
        const float sij = s * inv;
        const float c   = sij * inv;
        const int   sp  = species[edge_dst[e]];
        u16 h0 = f2h(sij);
        u16 h1 = f2h(c * vec[3*e+0]);
        u16 h2 = f2h(c * vec[3*e+1]);
        u16 h3 = f2h(c * vec[3*e+2]);
        h0 = (h0 & 0xFFFEu) | ((u16)( sp       & 1));
        h1 = (h1 & 0xFFFEu) | ((u16)((sp >> 1) & 1));
        h2 = (h2 & 0xFFFEu) | ((u16)((sp >> 2) & 1));
        h3 = (h3 & 0xFFFEu) | ((u16)((sp >> 3) & 1));
        const u32 lo = (u32)h0 | ((u32)h1 << 16);
        const u32 hi = (u32)h2 | ((u32)h3 << 16);
        EC8[e] = make_float2(__uint_as_float(lo), __uint_as_float(hi));
    } else if (bid < E_BLK + P_BLK) {
        int t = (bid - E_BLK) * 256 + tid;
        if (t < 3 * 4096) {
            int l = t >> 12, e = t & 4095, n = e >> 6, k = e & 63;
            const float* W = (l == 0) ? W1 : (l == 1) ? W2 : W3;
            u16* WT        = (l == 0) ? WT1 : (l == 1) ? WT2 : WT3;
            WT[n*64 + k] = f2h(W[k*64 + n]);
        }
        int u = t - 3 * 4096;
        if (u >= 0 && u < 256 * 64) {
            int sd = u >> 6, j = u & 63, s = sd >> 4, d = sd & 15;
            base_tab[u] = W0[(1+s)*64 + j] + W0[(17+d)*64 + j] + b0[j];
        }
    } else {
        int idx = (bid - E_BLK - P_BLK) * 256 + tid;
        if (idx < N_ATOMS) cnt[idx] = 0;
    }
}

// ---------------------------------------------------------------------------
// CSR build: histogram -> 3-stage parallel scan -> gather+scatter
// ---------------------------------------------------------------------------
__global__ __launch_bounds__(256) void hist_kernel(
    const int* __restrict__ a_ca, int* __restrict__ cnt)
{
    int i = (int)blockIdx.x * 256 + (int)threadIdx.x;
    if (i < N_ANGLES) atomicAdd(&cnt[a_ca[i]], 1);
}

__global__ __launch_bounds__(256) void scanA_kernel(
    const int* __restrict__ cnt, int* __restrict__ bsum)
{
    __shared__ int ws[4];
    const int t = (int)threadIdx.x;
    const int idx = (int)blockIdx.x * 256 + t;
    int v = (idx < N_ATOMS) ? cnt[idx] : 0;
    #pragma unroll
    for (int off = 32; off; off >>= 1) v += __shfl_down(v, off, 64);
    if ((t & 63) == 0) ws[t >> 6] = v;
    __syncthreads();
    if (t == 0) bsum[blockIdx.x] = ws[0] + ws[1] + ws[2] + ws[3];
}

__global__ __launch_bounds__(256) void scanB_kernel(
    const int* __restrict__ bsum, int* __restrict__ boff)
{
    __shared__ int sh[256];
    const int t = (int)threadIdx.x;
    int v = (t < SCAN_B) ? bsum[t] : 0;
    sh[t] = v;
    __syncthreads();
    for (int off = 1; off < 256; off <<= 1) {
        int u = (t >= off) ? sh[t - off] : 0;
        __syncthreads();
        sh[t] += u;
        __syncthreads();
    }
    if (t < SCAN_B) boff[t] = sh[t] - v;   // exclusive
}

__global__ __launch_bounds__(256) void scanC_kernel(
    const int* __restrict__ cnt, const int* __restrict__ boff,
    int* __restrict__ cursor)
{
    __shared__ int sh[256];
    const int t = (int)threadIdx.x;
    const int idx = (int)blockIdx.x * 256 + t;
    int v = (idx < N_ATOMS) ? cnt[idx] : 0;
    sh[t] = v;
    __syncthreads();
    for (int off = 1; off < 256; off <<= 1) {
        int u = (t >= off) ? sh[t - off] : 0;
        __syncthreads();
        sh[t] += u;
        __syncthreads();
    }
    if (idx < N_ATOMS) cursor[idx] = boff[blockIdx.x] + sh[t] - v;
}

// Writes atom-sorted 8B record per angle: {f32 theta, (tt_fx<<8)|pid}.
// Exactly TWO random loads per angle (species decoded from EC8 LSBs).
// tt_fx = table coord in fixed point with 15-bit fraction.
// After this kernel, cursor[a] == CSR row-END of atom a.
__global__ __launch_bounds__(256) void scatter_kernel(
    const int* __restrict__ a_src, const int* __restrict__ a_dst,
    const int* __restrict__ a_ca, const float2* __restrict__ EC8,
    int* __restrict__ cursor, float2* __restrict__ rec)
{
    int i = (int)blockIdx.x * 256 + (int)threadIdx.x;
    if (i >= N_ANGLES) return;
    const int se = a_src[i], de = a_dst[i], ca = a_ca[i];
    const float2 Es = EC8[se], Ed = EC8[de];
    const u32 slo = __float_as_uint(Es.x), shi = __float_as_uint(Es.y);
    const u32 dlo = __float_as_uint(Ed.x), dhi = __float_as_uint(Ed.y);
    const int s1 = (int)((slo & 1u) | ((slo >> 15) & 2u)
                       | ((shi & 1u) << 2) | ((shi >> 13) & 8u));
    const int s2 = (int)((dlo & 1u) | ((dlo >> 15) & 2u)
                       | ((dhi & 1u) << 2) | ((dhi >> 13) & 8u));
    const float theta = h2f((u16)slo) * h2f((u16)dlo)
                      + h2f((u16)(slo >> 16)) * h2f((u16)(dlo >> 16))
                      + h2f((u16)shi) * h2f((u16)dhi)
                      + h2f((u16)(shi >> 16)) * h2f((u16)(dhi >> 16));
    const int s = min(s1, s2), d = max(s1, s2);
    const int pid = s*16 - (s*(s-1))/2 + (d - s);

    // u = asinh(theta/8); tt = (u+UMAX)/h_u in [0, NT-1.001]
    const float x  = theta * 0.125f;
    const float ax = fabsf(x);
    float uu = __logf(ax + __fsqrt_rn(fmaf(ax, ax, 1.0f)));
    uu = copysignf(uu, x);
    const float tt = fminf(fmaxf(fmaf(uu, INV_HU, UMAX * INV_HU), 0.0f),
                           (float)NT - 1.001f);
    const u32 tfx = (u32)(tt * 32768.0f);          // 15-bit fraction

    const int pos = atomicAdd(&cursor[ca], 1);
    rec[pos] = make_float2(theta, __uint_as_float((tfx << 8) | (u32)pid));
}

// ---------------------------------------------------------------------------
// MFMA helpers (static indexing; LDS tile u16 index = row*64 + (col^((row&7)<<3)))
// ---------------------------------------------------------------------------
__device__ __forceinline__ void dense_mfma(const u16* __restrict__ strip,
    const u16* __restrict__ WT, int r15, int g4, f32x4 acc[4][4])
{
    #pragma unroll
    for (int kt = 0; kt < 2; ++kt) {
        f16x8 A[4], B[4];
        #pragma unroll
        for (int mt = 0; mt < 4; ++mt) {
            int row = mt*16 + r15;
            int col = (kt*32 + g4*8) ^ ((row & 7) << 3);
            A[mt] = *(const f16x8*)&strip[row*64 + col];
        }
        #pragma unroll
        for (int nt = 0; nt < 4; ++nt)
            B[nt] = *(const f16x8*)&WT[(nt*16 + r15)*64 + kt*32 + g4*8];
        #pragma unroll
        for (int mt = 0; mt < 4; ++mt) {
            #pragma unroll
            for (int nt = 0; nt < 4; ++nt)
                acc[mt][nt] = __builtin_amdgcn_mfma_f32_16x16x32_f16(
                    A[mt], B[nt], acc[mt][nt], 0, 0, 0);
        }
    }
}

__device__ __forceinline__ void act_store(u16* __restrict__ strip,
    const float* __restrict__ bias, int r15, int g4, f32x4 acc[4][4])
{
    float bn[4];
    #pragma unroll
    for (int nt = 0; nt < 4; ++nt) bn[nt] = bias[nt*16 + r15];
    #pragma unroll
    for (int mt = 0; mt < 4; ++mt) {
        #pragma unroll
        for (int r = 0; r < 4; ++r) {
            int row = mt*16 + g4*4 + r;
            int rsw = (row & 7) << 3;
            #pragma unroll
            for (int nt = 0; nt < 4; ++nt)
                strip[row*64 + ((nt*16 + r15) ^ rsw)] =
                    f2h(silu_f(acc[mt][nt][r] + bn[nt]));
        }
    }
}

// ---------------------------------------------------------------------------
// Table build: grid = 136 pairs x 2 m-passes (HALVES the serial chain — build
// was latency-bound at ~1 block/CU). Each block computes ONE MLP orientation
// for all 256 theta rows; partials Tp[m][pid][idx][j] summed in repack.
// ---------------------------------------------------------------------------
__global__ __launch_bounds__(256) void build_kernel(
    const float* __restrict__ W0, const float* __restrict__ base_tab,
    const u16* __restrict__ WT1, const u16* __restrict__ WT2,
    const u16* __restrict__ WT3,
    const float* __restrict__ b1, const float* __restrict__ b2,
    const float* __restrict__ b3,
    u16* __restrict__ Tp)
{
    __shared__ __align__(16) u16 act[256 * 64];   // 32 KB

    const int tid  = (int)threadIdx.x;
    const int lane = tid & 63;
    const int wv   = tid >> 6;
    const int r15  = lane & 15;
    const int g4   = lane >> 4;

    const int pid = (int)blockIdx.x >> 1;
    const int m   = (int)blockIdx.x & 1;
    // decode tri id -> (s, d), s <= d
    int s = 0, rem = pid;
    while (rem >= 16 - s) { rem -= 16 - s; ++s; }
    const int d = s + rem;

    const int idx = tid;                            // theta grid index
    const float u  = fmaf((float)idx, H_U, -UMAX);
    const float eu = __expf(u);
    const float theta = 4.0f * (eu - __frcp_rn(eu)); // 8*sinh(u)

    u16* strip = act + wv * 4096;

    f32x4 accG[4][4];
    #pragma unroll
    for (int nt = 0; nt < 4; ++nt) {
        float bv = b3[nt*16 + r15];                 // one b3 per partial
        #pragma unroll
        for (int mt = 0; mt < 4; ++mt) accG[mt][nt] = {bv, bv, bv, bv};
    }

    // layer 0 (one-hot collapsed)
    {
        const int p = m ? (d*16 + s) : (s*16 + d);
        const float4* bs4 = (const float4*)(base_tab + p*64);
        const float4* w04 = (const float4*)W0;
        const int rsw = (lane & 7) << 3;
        #pragma unroll
        for (int c = 0; c < 8; ++c) {
            float4 bl = bs4[2*c], bh = bs4[2*c+1];
            float4 wl = w04[2*c], wh = w04[2*c+1];
            u16x8 hv;
            hv[0] = f2h(silu_f(fmaf(theta, wl.x, bl.x)));
            hv[1] = f2h(silu_f(fmaf(theta, wl.y, bl.y)));
            hv[2] = f2h(silu_f(fmaf(theta, wl.z, bl.z)));
            hv[3] = f2h(silu_f(fmaf(theta, wl.w, bl.w)));
            hv[4] = f2h(silu_f(fmaf(theta, wh.x, bh.x)));
            hv[5] = f2h(silu_f(fmaf(theta, wh.y, bh.y)));
            hv[6] = f2h(silu_f(fmaf(theta, wh.z, bh.z)));
            hv[7] = f2h(silu_f(fmaf(theta, wh.w, bh.w)));
            *(u16x8*)&strip[lane*64 + ((c*8) ^ rsw)] = hv;
        }
    }
    // layer 1
    {
        f32x4 acc[4][4];
        #pragma unroll
        for (int mt = 0; mt < 4; ++mt)
            #pragma unroll
            for (int nt = 0; nt < 4; ++nt) acc[mt][nt] = {0.f,0.f,0.f,0.f};
        dense_mfma(strip, WT1, r15, g4, acc);
        act_store(strip, b1, r15, g4, acc);
    }
    // layer 2
    {
        f32x4 acc[4][4];
        #pragma unroll
        for (int mt = 0; mt < 4; ++mt)
            #pragma unroll
            for (int nt = 0; nt < 4; ++nt) acc[mt][nt] = {0.f,0.f,0.f,0.f};
        dense_mfma(strip, WT2, r15, g4, acc);
        act_store(strip, b2, r15, g4, acc);
    }
    // layer 3 -> accG
    dense_mfma(strip, WT3, r15, g4, accG);

    // stash partial G (f16) into act rows
    #pragma unroll
    for (int mt = 0; mt < 4; ++mt) {
        #pragma unroll
        for (int r = 0; r < 4; ++r) {
            int row = mt*16 + g4*4 + r;
            int rsw = (row & 7) << 3;
            #pragma unroll
            for (int nt = 0; nt < 4; ++nt)
                strip[row*64 + ((nt*16 + r15) ^ rsw)] = f2h(accG[mt][nt][r]);
        }
    }
    __syncthreads();

    // coalesced copy-out: thread tid owns act row tid -> Tp[m][pid][idx]
    u16* dst = Tp + (size_t)m * TSZ + ((size_t)pid * NT + (size_t)idx) * 64;
    const int rsw = (tid & 7) << 3;
    #pragma unroll
    for (int c = 0; c < 8; ++c)
        *(u16x8*)(dst + c*8) = *(const u16x8*)&act[tid*64 + ((c*8) ^ rsw)];
}

// ---------------------------------------------------------------------------
// Repack: sum the two m-partials and pair-pack rows i, i+1:
// T2[pid][i][lane] = pack(Ga+Gb @ row i, Ga+Gb @ row i+1)
// ---------------------------------------------------------------------------
__global__ __launch_bounds__(256) void repack_kernel(
    const u16* __restrict__ Tp, u32* __restrict__ T2)
{
    int idx = (int)blockIdx.x * 256 + (int)threadIdx.x;
    if (idx >= TSZ) return;
    const int row = (idx >> 6) & (NT - 1);
    const int nxt = (row < NT - 1) ? idx + 64 : idx;
    const float ga = h2f(Tp[idx]) + h2f(Tp[TSZ + idx]);
    const float gb = h2f(Tp[nxt]) + h2f(Tp[TSZ + nxt]);
    T2[idx] = (u32)f2h(ga) | ((u32)f2h(gb) << 16);
}

// ---------------------------------------------------------------------------
// Lookup: wave-per-atom CSR walk, lane = feature. Per angle: uniform 8B record
// (scalarized), one coalesced dword T2 load, lerp, f32 register accumulate.
// One direct store per atom row — no LDS, no atomics, no memset.
// ---------------------------------------------------------------------------
__global__ __launch_bounds__(256) void lookup_kernel(
    const float2* __restrict__ rec, const int* __restrict__ cursor,
    const u32* __restrict__ T2, float* __restrict__ out)
{
    const int tid  = (int)threadIdx.x;
    const int lane = tid & 63;
    const int wv   = tid >> 6;
    const int atom = (int)blockIdx.x * 4 + wv;
    if (atom >= N_ATOMS) return;

    const int start = atom ? cursor[atom - 1] : 0;
    const int end   = cursor[atom];

    float acc = 0.0f;
    for (int i = start; i < end; ++i) {
        const float2 rv = rec[__builtin_amdgcn_readfirstlane(i)];
        const float theta = rv.x;
        const u32 w   = __float_as_uint(rv.y);
        const u32 pid = w & 255u;
        const u32 tfx = w >> 8;
        const u32 i0  = tfx >> 15;
        const float fr = (float)(tfx & 32767u) * (1.0f / 32768.0f);
        const u32 off = (pid << 14) + (i0 << 6) + (u32)lane;  // pid*NT*64
        const u32 pr = T2[off];
        const float ga = h2f((u16)(pr & 0xFFFFu));
        const float gb = h2f((u16)(pr >> 16));
        acc = fmaf(fmaf(fr, gb - ga, ga), theta, acc);
    }
    out[(size_t)atom * 64 + lane] = acc;
}

extern "C" void kernel_launch(void* const* d_in, const int* in_sizes, int n_in,
                              void* d_out, int out_size, void* d_ws, size_t ws_size,
                              hipStream_t stream) {
    const int*   species   = (const int*)  d_in[0];
    const int*   edge_dst  = (const int*)  d_in[1];
    const float* distances = (const float*)d_in[2];
    const float* sw        = (const float*)d_in[3];
    const float* vec       = (const float*)d_in[4];
    const int*   a_src     = (const int*)  d_in[5];
    const int*   a_dst     = (const int*)  d_in[6];
    const int*   a_ca      = (const int*)  d_in[7];
    const float* W0 = (const float*)d_in[8];
    const float* b0 = (const float*)d_in[9];
    const float* W1 = (const float*)d_in[10];
    const float* b1 = (const float*)d_in[11];
    const float* W2 = (const float*)d_in[12];
    const float* b2 = (const float*)d_in[13];
    const float* W3 = (const float*)d_in[14];
    const float* b3 = (const float*)d_in[15];
    float* out = (float*)d_out;

    // ws: EC8 12.8M | cnt | cursor | bsum | boff | rec 12M | WT1/2/3 |
    //     base_tab | Tp 4.5M | T2 8.9M   (~39 MB)
    float2* EC8    = (float2*)d_ws;
    int*    cnt    = (int*)(EC8 + N_EDGES);
    int*    cursor = cnt + N_ATOMS;
    int*    bsum   = cursor + N_ATOMS;
    int*    boff   = bsum + SCAN_B;
    float2* rec    = (float2*)(boff + SCAN_B);
    u16*    WT1    = (u16*)(rec + N_ANGLES);
    u16*    WT2    = WT1 + 4096;
    u16*    WT3    = WT2 + 4096;
    float*  base_tab = (float*)(WT3 + 4096);
    u16*    Tp     = (u16*)(base_tab + 256*64);
    u32*    T2     = (u32*)(Tp + 2 * TSZ);

    fused_prep_kernel<<<E_BLK + P_BLK + Z_BLK, 256, 0, stream>>>(
        distances, sw, vec, edge_dst, species,
        W0, b0, W1, W2, W3, EC8, WT1, WT2, WT3, base_tab, cnt);
    hist_kernel<<<(N_ANGLES + 255) / 256, 256, 0, stream>>>(a_ca, cnt);
    scanA_kernel<<<SCAN_B, 256, 0, stream>>>(cnt, bsum);
    scanB_kernel<<<1, 256, 0, stream>>>(bsum, boff);
    scanC_kernel<<<SCAN_B, 256, 0, stream>>>(cnt, boff, cursor);
    scatter_kernel<<<(N_ANGLES + 255) / 256, 256, 0, stream>>>(
        a_src, a_dst, a_ca, EC8, cursor, rec);
    build_kernel<<<136 * 2, 256, 0, stream>>>(
        W0, base_tab, WT1, WT2, WT3, b1, b2, b3, Tp);
    repack_kernel<<<(TSZ + 255) / 256, 256, 0, stream>>>(Tp, T2);
    lookup_kernel<<<(N_ATOMS + 3) / 4, 256, 0, stream>>>(rec, cursor, T2, out);
}

// Round 12
// 254.592 us; speedup vs baseline: 1.4243x; 1.0799x over previous
//
#include <hip/hip_runtime.h>

#define N_ATOMS   50000
#define N_EDGES   1600000
#define N_ANGLES  1500000
#define SCAN_B    196            // ceil(N_ATOMS/256)

// theta-table: theta = 8*sinh(u), u uniform on [-UMAX, UMAX], NT points.
#define NT      256
#define UMAX    4.852092f
#define H_U     0.038055623f     // 2*UMAX/(NT-1)
#define INV_HU  26.277306f       // (NT-1)/(2*UMAX)
#define TSZ     (136 * NT * 64)  // one partial table

#define E_BLK   6250             // edge range blocks
#define P_BLK   112              // prep range blocks (3*4096+16384)/256
#define Z_BLK   196              // cnt-zero range blocks

typedef unsigned short u16;
typedef unsigned int   u32;
typedef _Float16 f16x8 __attribute__((ext_vector_type(8)));
typedef float    f32x4 __attribute__((ext_vector_type(4)));
typedef u16      u16x8 __attribute__((ext_vector_type(8)));

__device__ __forceinline__ float silu_f(float x) {
    return __fdividef(x, 1.0f + __expf(-x));
}
__device__ __forceinline__ u16 f2h(float x) {
    _Float16 h = (_Float16)x;
    return __builtin_bit_cast(u16, h);
}
__device__ __forceinline__ float h2f(u16 u) {
    return (float)__builtin_bit_cast(_Float16, u);
}

// ---------------------------------------------------------------------------
// Fused prep: [0,E_BLK) edge records (species embedded in f16 LSBs, 2^-11
// perturbation); [E_BLK,+P_BLK) weight transpose + base_tab; [+P_BLK,+Z_BLK)
// cnt zeroing (replaces hipMemsetAsync dispatch).
// ---------------------------------------------------------------------------
__global__ __launch_bounds__(256) void fused_prep_kernel(
    const float* __restrict__ distances, const float* __restrict__ sw,
    const float* __restrict__ vec, const int* __restrict__ edge_dst,
    const int* __restrict__ species,
    const float* __restrict__ W0, const float* __restrict__ b0,
    const float* __restrict__ W1, const float* __restrict__ W2,
    const float* __restrict__ W3,
    float2* __restrict__ EC8,
    u16* __restrict__ WT1, u16* __restrict__ WT2, u16* __restrict__ WT3,
    float* __restrict__ base_tab, int* __restrict__ cnt)
{
    const int bid = (int)blockIdx.x;
    const int tid = (int)threadIdx.x;

    if (bid < E_BLK) {
        int e = bid * 256 + tid;
        if (e >= N_EDGES) return;
        const float d   = distances[e];
        const float s   = sw[e];
        const float inv = 1.0f / d;
        const float sij = s * inv;
        const float c   = sij * inv;
        const int   sp  = species[edge_dst[e]];
        u16 h0 = f2h(sij);
        u16 h1 = f2h(c * vec[3*e+0]);
        u16 h2 = f2h(c * vec[3*e+1]);
        u16 h3 = f2h(c * vec[3*e+2]);
        h0 = (h0 & 0xFFFEu) | ((u16)( sp       & 1));
        h1 = (h1 & 0xFFFEu) | ((u16)((sp >> 1) & 1));
        h2 = (h2 & 0xFFFEu) | ((u16)((sp >> 2) & 1));
        h3 = (h3 & 0xFFFEu) | ((u16)((sp >> 3) & 1));
        const u32 lo = (u32)h0 | ((u32)h1 << 16);
        const u32 hi = (u32)h2 | ((u32)h3 << 16);
        EC8[e] = make_float2(__uint_as_float(lo), __uint_as_float(hi));
    } else if (bid < E_BLK + P_BLK) {
        int t = (bid - E_BLK) * 256 + tid;
        if (t < 3 * 4096) {
            int l = t >> 12, e = t & 4095, n = e >> 6, k = e & 63;
            const float* W = (l == 0) ? W1 : (l == 1) ? W2 : W3;
            u16* WT        = (l == 0) ? WT1 : (l == 1) ? WT2 : WT3;
            WT[n*64 + k] = f2h(W[k*64 + n]);
        }
        int u = t - 3 * 4096;
        if (u >= 0 && u < 256 * 64) {
            int sd = u >> 6, j = u & 63, s = sd >> 4, d = sd & 15;
            base_tab[u] = W0[(1+s)*64 + j] + W0[(17+d)*64 + j] + b0[j];
        }
    } else {
        int idx = (bid - E_BLK - P_BLK) * 256 + tid;
        if (idx < N_ATOMS) cnt[idx] = 0;
    }
}

// ---------------------------------------------------------------------------
// Histogram + rank capture: the atomicAdd's RETURN VALUE is this angle's rank
// within its atom. car[i] = (rank<<18)|ca — scatter then needs NO atomic.
// ---------------------------------------------------------------------------
__global__ __launch_bounds__(256) void hist_kernel(
    const int* __restrict__ a_ca, int* __restrict__ cnt, u32* __restrict__ car)
{
    int i = (int)blockIdx.x * 256 + (int)threadIdx.x;
    if (i < N_ANGLES) {
        const int ca = a_ca[i];
        const u32 rank = (u32)atomicAdd(&cnt[ca], 1);
        car[i] = (rank << 18) | (u32)ca;
    }
}

__global__ __launch_bounds__(256) void scanA_kernel(
    const int* __restrict__ cnt, int* __restrict__ bsum)
{
    __shared__ int ws[4];
    const int t = (int)threadIdx.x;
    const int idx = (int)blockIdx.x * 256 + t;
    int v = (idx < N_ATOMS) ? cnt[idx] : 0;
    #pragma unroll
    for (int off = 32; off; off >>= 1) v += __shfl_down(v, off, 64);
    if ((t & 63) == 0) ws[t >> 6] = v;
    __syncthreads();
    if (t == 0) bsum[blockIdx.x] = ws[0] + ws[1] + ws[2] + ws[3];
}

__global__ __launch_bounds__(256) void scanB_kernel(
    const int* __restrict__ bsum, int* __restrict__ boff)
{
    __shared__ int sh[256];
    const int t = (int)threadIdx.x;
    int v = (t < SCAN_B) ? bsum[t] : 0;
    sh[t] = v;
    __syncthreads();
    for (int off = 1; off < 256; off <<= 1) {
        int u = (t >= off) ? sh[t - off] : 0;
        __syncthreads();
        sh[t] += u;
        __syncthreads();
    }
    if (t < SCAN_B) boff[t] = sh[t] - v;   // exclusive
}

// cursor[a] = exclusive prefix (row START of atom a); sentinel
// cursor[N_ATOMS] = N_ANGLES written by the last atom's thread.
__global__ __launch_bounds__(256) void scanC_kernel(
    const int* __restrict__ cnt, const int* __restrict__ boff,
    int* __restrict__ cursor)
{
    __shared__ int sh[256];
    const int t = (int)threadIdx.x;
    const int idx = (int)blockIdx.x * 256 + t;
    int v = (idx < N_ATOMS) ? cnt[idx] : 0;
    sh[t] = v;
    __syncthreads();
    for (int off = 1; off < 256; off <<= 1) {
        int u = (t >= off) ? sh[t - off] : 0;
        __syncthreads();
        sh[t] += u;
        __syncthreads();
    }
    if (idx < N_ATOMS) {
        cursor[idx] = boff[blockIdx.x] + sh[t] - v;
        if (idx == N_ATOMS - 1) cursor[N_ATOMS] = boff[blockIdx.x] + sh[t];
    }
}

// Writes atom-sorted 8B record per angle: {f32 theta, (tt_fx<<8)|pid}.
// NO atomics: pos = cursor[ca] (read-only, 200KB L2-hot gather) + rank (from
// car). Exactly TWO random 64B-line gathers per angle (EC8 x2).
__global__ __launch_bounds__(256) void scatter_kernel(
    const int* __restrict__ a_src, const int* __restrict__ a_dst,
    const u32* __restrict__ car, const float2* __restrict__ EC8,
    const int* __restrict__ cursor, float2* __restrict__ rec)
{
    int i = (int)blockIdx.x * 256 + (int)threadIdx.x;
    if (i >= N_ANGLES) return;
    const int se = a_src[i], de = a_dst[i];
    const u32 cr = car[i];
    const int ca   = (int)(cr & 0x3FFFFu);
    const int rank = (int)(cr >> 18);
    const float2 Es = EC8[se], Ed = EC8[de];
    const u32 slo = __float_as_uint(Es.x), shi = __float_as_uint(Es.y);
    const u32 dlo = __float_as_uint(Ed.x), dhi = __float_as_uint(Ed.y);
    const int s1 = (int)((slo & 1u) | ((slo >> 15) & 2u)
                       | ((shi & 1u) << 2) | ((shi >> 13) & 8u));
    const int s2 = (int)((dlo & 1u) | ((dlo >> 15) & 2u)
                       | ((dhi & 1u) << 2) | ((dhi >> 13) & 8u));
    const float theta = h2f((u16)slo) * h2f((u16)dlo)
                      + h2f((u16)(slo >> 16)) * h2f((u16)(dlo >> 16))
                      + h2f((u16)shi) * h2f((u16)dhi)
                      + h2f((u16)(shi >> 16)) * h2f((u16)(dhi >> 16));
    const int s = min(s1, s2), d = max(s1, s2);
    const int pid = s*16 - (s*(s-1))/2 + (d - s);

    // u = asinh(theta/8); tt = (u+UMAX)/h_u in [0, NT-1.001]
    const float x  = theta * 0.125f;
    const float ax = fabsf(x);
    float uu = __logf(ax + __fsqrt_rn(fmaf(ax, ax, 1.0f)));
    uu = copysignf(uu, x);
    const float tt = fminf(fmaxf(fmaf(uu, INV_HU, UMAX * INV_HU), 0.0f),
                           (float)NT - 1.001f);
    const u32 tfx = (u32)(tt * 32768.0f);          // 15-bit fraction

    const int pos = cursor[ca] + rank;
    rec[pos] = make_float2(theta, __uint_as_float((tfx << 8) | (u32)pid));
}

// ---------------------------------------------------------------------------
// MFMA helpers (static indexing; LDS tile u16 index = row*64 + (col^((row&7)<<3)))
// ---------------------------------------------------------------------------
__device__ __forceinline__ void dense_mfma(const u16* __restrict__ strip,
    const u16* __restrict__ WT, int r15, int g4, f32x4 acc[4][4])
{
    #pragma unroll
    for (int kt = 0; kt < 2; ++kt) {
        f16x8 A[4], B[4];
        #pragma unroll
        for (int mt = 0; mt < 4; ++mt) {
            int row = mt*16 + r15;
            int col = (kt*32 + g4*8) ^ ((row & 7) << 3);
            A[mt] = *(const f16x8*)&strip[row*64 + col];
        }
        #pragma unroll
        for (int nt = 0; nt < 4; ++nt)
            B[nt] = *(const f16x8*)&WT[(nt*16 + r15)*64 + kt*32 + g4*8];
        #pragma unroll
        for (int mt = 0; mt < 4; ++mt) {
            #pragma unroll
            for (int nt = 0; nt < 4; ++nt)
                acc[mt][nt] = __builtin_amdgcn_mfma_f32_16x16x32_f16(
                    A[mt], B[nt], acc[mt][nt], 0, 0, 0);
        }
    }
}

__device__ __forceinline__ void act_store(u16* __restrict__ strip,
    const float* __restrict__ bias, int r15, int g4, f32x4 acc[4][4])
{
    float bn[4];
    #pragma unroll
    for (int nt = 0; nt < 4; ++nt) bn[nt] = bias[nt*16 + r15];
    #pragma unroll
    for (int mt = 0; mt < 4; ++mt) {
        #pragma unroll
        for (int r = 0; r < 4; ++r) {
            int row = mt*16 + g4*4 + r;
            int rsw = (row & 7) << 3;
            #pragma unroll
            for (int nt = 0; nt < 4; ++nt)
                strip[row*64 + ((nt*16 + r15) ^ rsw)] =
                    f2h(silu_f(acc[mt][nt][r] + bn[nt]));
        }
    }
}

// ---------------------------------------------------------------------------
// Table build: grid = 136 pairs x 2 m-passes (halves the serial chain).
// Partials Tp[m][pid][idx][j] summed in repack.
// ---------------------------------------------------------------------------
__global__ __launch_bounds__(256) void build_kernel(
    const float* __restrict__ W0, const float* __restrict__ base_tab,
    const u16* __restrict__ WT1, const u16* __restrict__ WT2,
    const u16* __restrict__ WT3,
    const float* __restrict__ b1, const float* __restrict__ b2,
    const float* __restrict__ b3,
    u16* __restrict__ Tp)
{
    __shared__ __align__(16) u16 act[256 * 64];   // 32 KB

    const int tid  = (int)threadIdx.x;
    const int lane = tid & 63;
    const int wv   = tid >> 6;
    const int r15  = lane & 15;
    const int g4   = lane >> 4;

    const int pid = (int)blockIdx.x >> 1;
    const int m   = (int)blockIdx.x & 1;
    // decode tri id -> (s, d), s <= d
    int s = 0, rem = pid;
    while (rem >= 16 - s) { rem -= 16 - s; ++s; }
    const int d = s + rem;

    const int idx = tid;                            // theta grid index
    const float u  = fmaf((float)idx, H_U, -UMAX);
    const float eu = __expf(u);
    const float theta = 4.0f * (eu - __frcp_rn(eu)); // 8*sinh(u)

    u16* strip = act + wv * 4096;

    f32x4 accG[4][4];
    #pragma unroll
    for (int nt = 0; nt < 4; ++nt) {
        float bv = b3[nt*16 + r15];                 // one b3 per partial
        #pragma unroll
        for (int mt = 0; mt < 4; ++mt) accG[mt][nt] = {bv, bv, bv, bv};
    }

    // layer 0 (one-hot collapsed)
    {
        const int p = m ? (d*16 + s) : (s*16 + d);
        const float4* bs4 = (const float4*)(base_tab + p*64);
        const float4* w04 = (const float4*)W0;
        const int rsw = (lane & 7) << 3;
        #pragma unroll
        for (int c = 0; c < 8; ++c) {
            float4 bl = bs4[2*c], bh = bs4[2*c+1];
            float4 wl = w04[2*c], wh = w04[2*c+1];
            u16x8 hv;
            hv[0] = f2h(silu_f(fmaf(theta, wl.x, bl.x)));
            hv[1] = f2h(silu_f(fmaf(theta, wl.y, bl.y)));
            hv[2] = f2h(silu_f(fmaf(theta, wl.z, bl.z)));
            hv[3] = f2h(silu_f(fmaf(theta, wl.w, bl.w)));
            hv[4] = f2h(silu_f(fmaf(theta, wh.x, bh.x)));
            hv[5] = f2h(silu_f(fmaf(theta, wh.y, bh.y)));
            hv[6] = f2h(silu_f(fmaf(theta, wh.z, bh.z)));
            hv[7] = f2h(silu_f(fmaf(theta, wh.w, bh.w)));
            *(u16x8*)&strip[lane*64 + ((c*8) ^ rsw)] = hv;
        }
    }
    // layer 1
    {
        f32x4 acc[4][4];
        #pragma unroll
        for (int mt = 0; mt < 4; ++mt)
            #pragma unroll
            for (int nt = 0; nt < 4; ++nt) acc[mt][nt] = {0.f,0.f,0.f,0.f};
        dense_mfma(strip, WT1, r15, g4, acc);
        act_store(strip, b1, r15, g4, acc);
    }
    // layer 2
    {
        f32x4 acc[4][4];
        #pragma unroll
        for (int mt = 0; mt < 4; ++mt)
            #pragma unroll
            for (int nt = 0; nt < 4; ++nt) acc[mt][nt] = {0.f,0.f,0.f,0.f};
        dense_mfma(strip, WT2, r15, g4, acc);
        act_store(strip, b2, r15, g4, acc);
    }
    // layer 3 -> accG
    dense_mfma(strip, WT3, r15, g4, accG);

    // stash partial G (f16) into act rows
    #pragma unroll
    for (int mt = 0; mt < 4; ++mt) {
        #pragma unroll
        for (int r = 0; r < 4; ++r) {
            int row = mt*16 + g4*4 + r;
            int rsw = (row & 7) << 3;
            #pragma unroll
            for (int nt = 0; nt < 4; ++nt)
                strip[row*64 + ((nt*16 + r15) ^ rsw)] = f2h(accG[mt][nt][r]);
        }
    }
    __syncthreads();

    // coalesced copy-out: thread tid owns act row tid -> Tp[m][pid][idx]
    u16* dst = Tp + (size_t)m * TSZ + ((size_t)pid * NT + (size_t)idx) * 64;
    const int rsw = (tid & 7) << 3;
    #pragma unroll
    for (int c = 0; c < 8; ++c)
        *(u16x8*)(dst + c*8) = *(const u16x8*)&act[tid*64 + ((c*8) ^ rsw)];
}

// ---------------------------------------------------------------------------
// Repack: sum the two m-partials and pair-pack rows i, i+1:
// T2[pid][i][lane] = pack(Ga+Gb @ row i, Ga+Gb @ row i+1)
// ---------------------------------------------------------------------------
__global__ __launch_bounds__(256) void repack_kernel(
    const u16* __restrict__ Tp, u32* __restrict__ T2)
{
    int idx = (int)blockIdx.x * 256 + (int)threadIdx.x;
    if (idx >= TSZ) return;
    const int row = (idx >> 6) & (NT - 1);
    const int nxt = (row < NT - 1) ? idx + 64 : idx;
    const float ga = h2f(Tp[idx]) + h2f(Tp[TSZ + idx]);
    const float gb = h2f(Tp[nxt]) + h2f(Tp[TSZ + nxt]);
    T2[idx] = (u32)f2h(ga) | ((u32)f2h(gb) << 16);
}

// ---------------------------------------------------------------------------
// Lookup: wave-per-atom CSR walk, lane = feature. Per angle: uniform 8B record
// (scalarized), one coalesced dword T2 load, lerp, f32 register accumulate.
// One direct store per atom row — no LDS, no atomics, no memset.
// cursor is exclusive: start = cursor[atom], end = cursor[atom+1].
// ---------------------------------------------------------------------------
__global__ __launch_bounds__(256) void lookup_kernel(
    const float2* __restrict__ rec, const int* __restrict__ cursor,
    const u32* __restrict__ T2, float* __restrict__ out)
{
    const int tid  = (int)threadIdx.x;
    const int lane = tid & 63;
    const int wv   = tid >> 6;
    const int atom = (int)blockIdx.x * 4 + wv;
    if (atom >= N_ATOMS) return;

    const int start = cursor[atom];
    const int end   = cursor[atom + 1];

    float acc = 0.0f;
    for (int i = start; i < end; ++i) {
        const float2 rv = rec[__builtin_amdgcn_readfirstlane(i)];
        const float theta = rv.x;
        const u32 w   = __float_as_uint(rv.y);
        const u32 pid = w & 255u;
        const u32 tfx = w >> 8;
        const u32 i0  = tfx >> 15;
        const float fr = (float)(tfx & 32767u) * (1.0f / 32768.0f);
        const u32 off = (pid << 14) + (i0 << 6) + (u32)lane;  // pid*NT*64
        const u32 pr = T2[off];
        const float ga = h2f((u16)(pr & 0xFFFFu));
        const float gb = h2f((u16)(pr >> 16));
        acc = fmaf(fmaf(fr, gb - ga, ga), theta, acc);
    }
    out[(size_t)atom * 64 + lane] = acc;
}

extern "C" void kernel_launch(void* const* d_in, const int* in_sizes, int n_in,
                              void* d_out, int out_size, void* d_ws, size_t ws_size,
                              hipStream_t stream) {
    const int*   species   = (const int*)  d_in[0];
    const int*   edge_dst  = (const int*)  d_in[1];
    const float* distances = (const float*)d_in[2];
    const float* sw        = (const float*)d_in[3];
    const float* vec       = (const float*)d_in[4];
    const int*   a_src     = (const int*)  d_in[5];
    const int*   a_dst     = (const int*)  d_in[6];
    const int*   a_ca      = (const int*)  d_in[7];
    const float* W0 = (const float*)d_in[8];
    const float* b0 = (const float*)d_in[9];
    const float* W1 = (const float*)d_in[10];
    const float* b1 = (const float*)d_in[11];
    const float* W2 = (const float*)d_in[12];
    const float* b2 = (const float*)d_in[13];
    const float* W3 = (const float*)d_in[14];
    const float* b3 = (const float*)d_in[15];
    float* out = (float*)d_out;

    // ws: EC8 12.8M | cnt | cursor(+1) | bsum | boff | car 6M | rec 12M |
    //     WT1/2/3 | base_tab | Tp 4.5M | T2 8.9M   (~45 MB)
    float2* EC8    = (float2*)d_ws;
    int*    cnt    = (int*)(EC8 + N_EDGES);
    int*    cursor = cnt + N_ATOMS;
    int*    bsum   = cursor + N_ATOMS + 1;
    int*    boff   = bsum + SCAN_B;
    u32*    car    = (u32*)(boff + SCAN_B + 1);   // +1 pad keeps rec 8B-aligned
    float2* rec    = (float2*)(car + N_ANGLES);
    u16*    WT1    = (u16*)(rec + N_ANGLES);
    u16*    WT2    = WT1 + 4096;
    u16*    WT3    = WT2 + 4096;
    float*  base_tab = (float*)(WT3 + 4096);
    u16*    Tp     = (u16*)(base_tab + 256*64);
    u32*    T2     = (u32*)(Tp + 2 * TSZ);

    fused_prep_kernel<<<E_BLK + P_BLK + Z_BLK, 256, 0, stream>>>(
        distances, sw, vec, edge_dst, species,
        W0, b0, W1, W2, W3, EC8, WT1, WT2, WT3, base_tab, cnt);
    hist_kernel<<<(N_ANGLES + 255) / 256, 256, 0, stream>>>(a_ca, cnt, car);
    scanA_kernel<<<SCAN_B, 256, 0, stream>>>(cnt, bsum);
    scanB_kernel<<<1, 256, 0, stream>>>(bsum, boff);
    scanC_kernel<<<SCAN_B, 256, 0, stream>>>(cnt, boff, cursor);
    scatter_kernel<<<(N_ANGLES + 255) / 256, 256, 0, stream>>>(
        a_src, a_dst, car, EC8, cursor, rec);
    build_kernel<<<136 * 2, 256, 0, stream>>>(
        W0, base_tab, WT1, WT2, WT3, b1, b2, b3, Tp);
    repack_kernel<<<(TSZ + 255) / 256, 256, 0, stream>>>(Tp, T2);
    lookup_kernel<<<(N_ATOMS + 3) / 4, 256, 0, stream>>>(rec, cursor, T2, out);
}

// Round 13
// 210.224 us; speedup vs baseline: 1.7249x; 1.2110x over previous
//
#include <hip/hip_runtime.h>

#define N_ATOMS   50000
#define N_EDGES   1600000
#define N_ANGLES  1500000
#define SCAN_B    196            // ceil(N_ATOMS/256)

// theta-table: theta = 8*sinh(u), u uniform on [-UMAX, UMAX], NT points.
#define NT      256
#define UMAX    4.852092f
#define H_U     0.038055623f     // 2*UMAX/(NT-1)
#define INV_HU  26.277306f       // (NT-1)/(2*UMAX)
#define TSZ     (136 * NT * 64)  // one partial table

#define E_BLK   6250             // edge range blocks
#define P_BLK   112              // prep range blocks (3*4096+16384)/256
#define Z_BLK   196              // cnt-zero range blocks

typedef unsigned short u16;
typedef unsigned int   u32;
typedef _Float16 f16x8 __attribute__((ext_vector_type(8)));
typedef float    f32x4 __attribute__((ext_vector_type(4)));
typedef u16      u16x8 __attribute__((ext_vector_type(8)));

__device__ __forceinline__ float silu_f(float x) {
    return __fdividef(x, 1.0f + __expf(-x));
}
__device__ __forceinline__ u16 f2h(float x) {
    _Float16 h = (_Float16)x;
    return __builtin_bit_cast(u16, h);
}
__device__ __forceinline__ float h2f(u16 u) {
    return (float)__builtin_bit_cast(_Float16, u);
}

// ---------------------------------------------------------------------------
// Fused prep: [0,E_BLK) edge records (species embedded in f16 LSBs);
// [E_BLK,+P_BLK) weight transpose + base_tab; [+P_BLK,+Z_BLK) cnt zeroing.
// ---------------------------------------------------------------------------
__global__ __launch_bounds__(256) void fused_prep_kernel(
    const float* __restrict__ distances, const float* __restrict__ sw,
    const float* __restrict__ vec, const int* __restrict__ edge_dst,
    const int* __restrict__ species,
    const float* __restrict__ W0, const float* __restrict__ b0,
    const float* __restrict__ W1, const float* __restrict__ W2,
    const float* __restrict__ W3,
    float2* __restrict__ EC8,
    u16* __restrict__ WT1, u16* __restrict__ WT2, u16* __restrict__ WT3,
    float* __restrict__ base_tab, int* __restrict__ cnt)
{
    const int bid = (int)blockIdx.x;
    const int tid = (int)threadIdx.x;

    if (bid < E_BLK) {
        int e = bid * 256 + tid;
        if (e >= N_EDGES) return;
        const float d   = distances[e];
        const float s   = sw[e];
        const float inv = 1.0f / d;
        const float sij = s * inv;
        const float c   = sij * inv;
        const int   sp  = species[edge_dst[e]];
        u16 h0 = f2h(sij);
        u16 h1 = f2h(c * vec[3*e+0]);
        u16 h2 = f2h(c * vec[3*e+1]);
        u16 h3 = f2h(c * vec[3*e+2]);
        h0 = (h0 & 0xFFFEu) | ((u16)( sp       & 1));
        h1 = (h1 & 0xFFFEu) | ((u16)((sp >> 1) & 1));
        h2 = (h2 & 0xFFFEu) | ((u16)((sp >> 2) & 1));
        h3 = (h3 & 0xFFFEu) | ((u16)((sp >> 3) & 1));
        const u32 lo = (u32)h0 | ((u32)h1 << 16);
        const u32 hi = (u32)h2 | ((u32)h3 << 16);
        EC8[e] = make_float2(__uint_as_float(lo), __uint_as_float(hi));
    } else if (bid < E_BLK + P_BLK) {
        int t = (bid - E_BLK) * 256 + tid;
        if (t < 3 * 4096) {
            int l = t >> 12, e = t & 4095, n = e >> 6, k = e & 63;
            const float* W = (l == 0) ? W1 : (l == 1) ? W2 : W3;
            u16* WT        = (l == 0) ? WT1 : (l == 1) ? WT2 : WT3;
            WT[n*64 + k] = f2h(W[k*64 + n]);
        }
        int u = t - 3 * 4096;
        if (u >= 0 && u < 256 * 64) {
            int sd = u >> 6, j = u & 63, s = sd >> 4, d = sd & 15;
            base_tab[u] = W0[(1+s)*64 + j] + W0[(17+d)*64 + j] + b0[j];
        }
    } else {
        int idx = (bid - E_BLK - P_BLK) * 256 + tid;
        if (idx < N_ATOMS) cnt[idx] = 0;
    }
}

// ---------------------------------------------------------------------------
// Fused angle prep: rank-atomic (latency overlaps the 2 independent EC8
// gathers in flight) + theta/pid/table-coord math + coalesced writes of the
// unsorted record and the (rank,ca) handle. Replaces hist + gather-scatter.
// ---------------------------------------------------------------------------
__global__ __launch_bounds__(256) void angle_prep_kernel(
    const int* __restrict__ a_src, const int* __restrict__ a_dst,
    const int* __restrict__ a_ca, const float2* __restrict__ EC8,
    int* __restrict__ cnt, u32* __restrict__ car, float2* __restrict__ recU)
{
    int i = (int)blockIdx.x * 256 + (int)threadIdx.x;
    if (i >= N_ANGLES) return;
    const int se = a_src[i], de = a_dst[i], ca = a_ca[i];
    const float2 Es = EC8[se], Ed = EC8[de];   // 2 random lines, in flight with atomic
    const u32 rank = (u32)atomicAdd(&cnt[ca], 1);

    const u32 slo = __float_as_uint(Es.x), shi = __float_as_uint(Es.y);
    const u32 dlo = __float_as_uint(Ed.x), dhi = __float_as_uint(Ed.y);
    const int s1 = (int)((slo & 1u) | ((slo >> 15) & 2u)
                       | ((shi & 1u) << 2) | ((shi >> 13) & 8u));
    const int s2 = (int)((dlo & 1u) | ((dlo >> 15) & 2u)
                       | ((dhi & 1u) << 2) | ((dhi >> 13) & 8u));
    const float theta = h2f((u16)slo) * h2f((u16)dlo)
                      + h2f((u16)(slo >> 16)) * h2f((u16)(dlo >> 16))
                      + h2f((u16)shi) * h2f((u16)dhi)
                      + h2f((u16)(shi >> 16)) * h2f((u16)(dhi >> 16));
    const int s = min(s1, s2), d = max(s1, s2);
    const int pid = s*16 - (s*(s-1))/2 + (d - s);

    // u = asinh(theta/8); tt = (u+UMAX)/h_u in [0, NT-1.001]
    const float x  = theta * 0.125f;
    const float ax = fabsf(x);
    float uu = __logf(ax + __fsqrt_rn(fmaf(ax, ax, 1.0f)));
    uu = copysignf(uu, x);
    const float tt = fminf(fmaxf(fmaf(uu, INV_HU, UMAX * INV_HU), 0.0f),
                           (float)NT - 1.001f);
    const u32 tfx = (u32)(tt * 32768.0f);          // 15-bit fraction

    car[i]  = (rank << 18) | (u32)ca;
    recU[i] = make_float2(theta, __uint_as_float((tfx << 8) | (u32)pid));
}

__global__ __launch_bounds__(256) void scanA_kernel(
    const int* __restrict__ cnt, int* __restrict__ bsum)
{
    __shared__ int ws[4];
    const int t = (int)threadIdx.x;
    const int idx = (int)blockIdx.x * 256 + t;
    int v = (idx < N_ATOMS) ? cnt[idx] : 0;
    #pragma unroll
    for (int off = 32; off; off >>= 1) v += __shfl_down(v, off, 64);
    if ((t & 63) == 0) ws[t >> 6] = v;
    __syncthreads();
    if (t == 0) bsum[blockIdx.x] = ws[0] + ws[1] + ws[2] + ws[3];
}

__global__ __launch_bounds__(256) void scanB_kernel(
    const int* __restrict__ bsum, int* __restrict__ boff)
{
    __shared__ int sh[256];
    const int t = (int)threadIdx.x;
    int v = (t < SCAN_B) ? bsum[t] : 0;
    sh[t] = v;
    __syncthreads();
    for (int off = 1; off < 256; off <<= 1) {
        int u = (t >= off) ? sh[t - off] : 0;
        __syncthreads();
        sh[t] += u;
        __syncthreads();
    }
    if (t < SCAN_B) boff[t] = sh[t] - v;   // exclusive
}

// cursor[a] = exclusive prefix (row START of atom a); sentinel cursor[N_ATOMS].
__global__ __launch_bounds__(256) void scanC_kernel(
    const int* __restrict__ cnt, const int* __restrict__ boff,
    int* __restrict__ cursor)
{
    __shared__ int sh[256];
    const int t = (int)threadIdx.x;
    const int idx = (int)blockIdx.x * 256 + t;
    int v = (idx < N_ATOMS) ? cnt[idx] : 0;
    sh[t] = v;
    __syncthreads();
    for (int off = 1; off < 256; off <<= 1) {
        int u = (t >= off) ? sh[t - off] : 0;
        __syncthreads();
        sh[t] += u;
        __syncthreads();
    }
    if (idx < N_ATOMS) {
        cursor[idx] = boff[blockIdx.x] + sh[t] - v;
        if (idx == N_ATOMS - 1) cursor[N_ATOMS] = boff[blockIdx.x] + sh[t];
    }
}

// ---------------------------------------------------------------------------
// Pure permutation: rec[cursor[ca]+rank] = recU[i]. Coalesced reads; the
// random 8B write granule is the irreducible cost of the sort.
// ---------------------------------------------------------------------------
__global__ __launch_bounds__(256) void permute_kernel(
    const float2* __restrict__ recU, const u32* __restrict__ car,
    const int* __restrict__ cursor, float2* __restrict__ rec)
{
    int i = (int)blockIdx.x * 256 + (int)threadIdx.x;
    if (i >= N_ANGLES) return;
    const u32 cr = car[i];
    const int ca   = (int)(cr & 0x3FFFFu);
    const int rank = (int)(cr >> 18);
    rec[cursor[ca] + rank] = recU[i];
}

// ---------------------------------------------------------------------------
// MFMA helpers (static indexing; LDS tile u16 index = row*64 + (col^((row&7)<<3)))
// ---------------------------------------------------------------------------
__device__ __forceinline__ void dense_mfma(const u16* __restrict__ strip,
    const u16* __restrict__ WT, int r15, int g4, f32x4 acc[4][4])
{
    #pragma unroll
    for (int kt = 0; kt < 2; ++kt) {
        f16x8 A[4], B[4];
        #pragma unroll
        for (int mt = 0; mt < 4; ++mt) {
            int row = mt*16 + r15;
            int col = (kt*32 + g4*8) ^ ((row & 7) << 3);
            A[mt] = *(const f16x8*)&strip[row*64 + col];
        }
        #pragma unroll
        for (int nt = 0; nt < 4; ++nt)
            B[nt] = *(const f16x8*)&WT[(nt*16 + r15)*64 + kt*32 + g4*8];
        #pragma unroll
        for (int mt = 0; mt < 4; ++mt) {
            #pragma unroll
            for (int nt = 0; nt < 4; ++nt)
                acc[mt][nt] = __builtin_amdgcn_mfma_f32_16x16x32_f16(
                    A[mt], B[nt], acc[mt][nt], 0, 0, 0);
        }
    }
}

__device__ __forceinline__ void act_store(u16* __restrict__ strip,
    const float* __restrict__ bias, int r15, int g4, f32x4 acc[4][4])
{
    float bn[4];
    #pragma unroll
    for (int nt = 0; nt < 4; ++nt) bn[nt] = bias[nt*16 + r15];
    #pragma unroll
    for (int mt = 0; mt < 4; ++mt) {
        #pragma unroll
        for (int r = 0; r < 4; ++r) {
            int row = mt*16 + g4*4 + r;
            int rsw = (row & 7) << 3;
            #pragma unroll
            for (int nt = 0; nt < 4; ++nt)
                strip[row*64 + ((nt*16 + r15) ^ rsw)] =
                    f2h(silu_f(acc[mt][nt][r] + bn[nt]));
        }
    }
}

// ---------------------------------------------------------------------------
// Table build: grid = 136 pairs x 2 m-passes. Partials summed in repack.
// ---------------------------------------------------------------------------
__global__ __launch_bounds__(256) void build_kernel(
    const float* __restrict__ W0, const float* __restrict__ base_tab,
    const u16* __restrict__ WT1, const u16* __restrict__ WT2,
    const u16* __restrict__ WT3,
    const float* __restrict__ b1, const float* __restrict__ b2,
    const float* __restrict__ b3,
    u16* __restrict__ Tp)
{
    __shared__ __align__(16) u16 act[256 * 64];   // 32 KB

    const int tid  = (int)threadIdx.x;
    const int lane = tid & 63;
    const int wv   = tid >> 6;
    const int r15  = lane & 15;
    const int g4   = lane >> 4;

    const int pid = (int)blockIdx.x >> 1;
    const int m   = (int)blockIdx.x & 1;
    // decode tri id -> (s, d), s <= d
    int s = 0, rem = pid;
    while (rem >= 16 - s) { rem -= 16 - s; ++s; }
    const int d = s + rem;

    const int idx = tid;                            // theta grid index
    const float u  = fmaf((float)idx, H_U, -UMAX);
    const float eu = __expf(u);
    const float theta = 4.0f * (eu - __frcp_rn(eu)); // 8*sinh(u)

    u16* strip = act + wv * 4096;

    f32x4 accG[4][4];
    #pragma unroll
    for (int nt = 0; nt < 4; ++nt) {
        float bv = b3[nt*16 + r15];                 // one b3 per partial
        #pragma unroll
        for (int mt = 0; mt < 4; ++mt) accG[mt][nt] = {bv, bv, bv, bv};
    }

    // layer 0 (one-hot collapsed)
    {
        const int p = m ? (d*16 + s) : (s*16 + d);
        const float4* bs4 = (const float4*)(base_tab + p*64);
        const float4* w04 = (const float4*)W0;
        const int rsw = (lane & 7) << 3;
        #pragma unroll
        for (int c = 0; c < 8; ++c) {
            float4 bl = bs4[2*c], bh = bs4[2*c+1];
            float4 wl = w04[2*c], wh = w04[2*c+1];
            u16x8 hv;
            hv[0] = f2h(silu_f(fmaf(theta, wl.x, bl.x)));
            hv[1] = f2h(silu_f(fmaf(theta, wl.y, bl.y)));
            hv[2] = f2h(silu_f(fmaf(theta, wl.z, bl.z)));
            hv[3] = f2h(silu_f(fmaf(theta, wl.w, bl.w)));
            hv[4] = f2h(silu_f(fmaf(theta, wh.x, bh.x)));
            hv[5] = f2h(silu_f(fmaf(theta, wh.y, bh.y)));
            hv[6] = f2h(silu_f(fmaf(theta, wh.z, bh.z)));
            hv[7] = f2h(silu_f(fmaf(theta, wh.w, bh.w)));
            *(u16x8*)&strip[lane*64 + ((c*8) ^ rsw)] = hv;
        }
    }
    // layer 1
    {
        f32x4 acc[4][4];
        #pragma unroll
        for (int mt = 0; mt < 4; ++mt)
            #pragma unroll
            for (int nt = 0; nt < 4; ++nt) acc[mt][nt] = {0.f,0.f,0.f,0.f};
        dense_mfma(strip, WT1, r15, g4, acc);
        act_store(strip, b1, r15, g4, acc);
    }
    // layer 2
    {
        f32x4 acc[4][4];
        #pragma unroll
        for (int mt = 0; mt < 4; ++mt)
            #pragma unroll
            for (int nt = 0; nt < 4; ++nt) acc[mt][nt] = {0.f,0.f,0.f,0.f};
        dense_mfma(strip, WT2, r15, g4, acc);
        act_store(strip, b2, r15, g4, acc);
    }
    // layer 3 -> accG
    dense_mfma(strip, WT3, r15, g4, accG);

    // stash partial G (f16) into act rows
    #pragma unroll
    for (int mt = 0; mt < 4; ++mt) {
        #pragma unroll
        for (int r = 0; r < 4; ++r) {
            int row = mt*16 + g4*4 + r;
            int rsw = (row & 7) << 3;
            #pragma unroll
            for (int nt = 0; nt < 4; ++nt)
                strip[row*64 + ((nt*16 + r15) ^ rsw)] = f2h(accG[mt][nt][r]);
        }
    }
    __syncthreads();

    // coalesced copy-out: thread tid owns act row tid -> Tp[m][pid][idx]
    u16* dst = Tp + (size_t)m * TSZ + ((size_t)pid * NT + (size_t)idx) * 64;
    const int rsw = (tid & 7) << 3;
    #pragma unroll
    for (int c = 0; c < 8; ++c)
        *(u16x8*)(dst + c*8) = *(const u16x8*)&act[tid*64 + ((c*8) ^ rsw)];
}

// ---------------------------------------------------------------------------
// Repack: sum the two m-partials and pair-pack rows i, i+1.
// ---------------------------------------------------------------------------
__global__ __launch_bounds__(256) void repack_kernel(
    const u16* __restrict__ Tp, u32* __restrict__ T2)
{
    int idx = (int)blockIdx.x * 256 + (int)threadIdx.x;
    if (idx >= TSZ) return;
    const int row = (idx >> 6) & (NT - 1);
    const int nxt = (row < NT - 1) ? idx + 64 : idx;
    const float ga = h2f(Tp[idx]) + h2f(Tp[TSZ + idx]);
    const float gb = h2f(Tp[nxt]) + h2f(Tp[TSZ + nxt]);
    T2[idx] = (u32)f2h(ga) | ((u32)f2h(gb) << 16);
}

// ---------------------------------------------------------------------------
// Lookup: wave-per-atom CSR walk, lane = feature, UNROLL x2 with dual
// accumulators -> 2 independent T2 loads in flight per wave (the serial
// chain was the R12 limiter). Scalarized record reads; one store per atom.
// ---------------------------------------------------------------------------
__global__ __launch_bounds__(256) void lookup_kernel(
    const float2* __restrict__ rec, const int* __restrict__ cursor,
    const u32* __restrict__ T2, float* __restrict__ out)
{
    const int tid  = (int)threadIdx.x;
    const int lane = tid & 63;
    const int wv   = tid >> 6;
    const int atom = (int)blockIdx.x * 4 + wv;
    if (atom >= N_ATOMS) return;

    const int start = cursor[atom];
    const int end   = cursor[atom + 1];

    float acc0 = 0.0f, acc1 = 0.0f;
    int i = start;
    for (; i + 1 < end; i += 2) {
        const float2 rv0 = rec[__builtin_amdgcn_readfirstlane(i)];
        const float2 rv1 = rec[__builtin_amdgcn_readfirstlane(i + 1)];
        const u32 w0 = __float_as_uint(rv0.y);
        const u32 w1 = __float_as_uint(rv1.y);
        const u32 off0 = ((w0 & 255u) << 14) + ((w0 >> 23) << 6) + (u32)lane;
        const u32 off1 = ((w1 & 255u) << 14) + ((w1 >> 23) << 6) + (u32)lane;
        const u32 pr0 = T2[off0];
        const u32 pr1 = T2[off1];
        const float fr0 = (float)((w0 >> 8) & 32767u) * (1.0f / 32768.0f);
        const float fr1 = (float)((w1 >> 8) & 32767u) * (1.0f / 32768.0f);
        const float ga0 = h2f((u16)(pr0 & 0xFFFFu));
        const float gb0 = h2f((u16)(pr0 >> 16));
        const float ga1 = h2f((u16)(pr1 & 0xFFFFu));
        const float gb1 = h2f((u16)(pr1 >> 16));
        acc0 = fmaf(fmaf(fr0, gb0 - ga0, ga0), rv0.x, acc0);
        acc1 = fmaf(fmaf(fr1, gb1 - ga1, ga1), rv1.x, acc1);
    }
    if (i < end) {
        const float2 rv = rec[__builtin_amdgcn_readfirstlane(i)];
        const u32 w = __float_as_uint(rv.y);
        const u32 off = ((w & 255u) << 14) + ((w >> 23) << 6) + (u32)lane;
        const u32 pr = T2[off];
        const float fr = (float)((w >> 8) & 32767u) * (1.0f / 32768.0f);
        const float ga = h2f((u16)(pr & 0xFFFFu));
        const float gb = h2f((u16)(pr >> 16));
        acc0 = fmaf(fmaf(fr, gb - ga, ga), rv.x, acc0);
    }
    out[(size_t)atom * 64 + lane] = acc0 + acc1;
}

extern "C" void kernel_launch(void* const* d_in, const int* in_sizes, int n_in,
                              void* d_out, int out_size, void* d_ws, size_t ws_size,
                              hipStream_t stream) {
    const int*   species   = (const int*)  d_in[0];
    const int*   edge_dst  = (const int*)  d_in[1];
    const float* distances = (const float*)d_in[2];
    const float* sw        = (const float*)d_in[3];
    const float* vec       = (const float*)d_in[4];
    const int*   a_src     = (const int*)  d_in[5];
    const int*   a_dst     = (const int*)  d_in[6];
    const int*   a_ca      = (const int*)  d_in[7];
    const float* W0 = (const float*)d_in[8];
    const float* b0 = (const float*)d_in[9];
    const float* W1 = (const float*)d_in[10];
    const float* b1 = (const float*)d_in[11];
    const float* W2 = (const float*)d_in[12];
    const float* b2 = (const float*)d_in[13];
    const float* W3 = (const float*)d_in[14];
    const float* b3 = (const float*)d_in[15];
    float* out = (float*)d_out;

    // ws: EC8 12.8M | cnt | cursor(+1) | bsum | boff(+pad) | car 6M |
    //     recU 12M | rec 12M | WT1/2/3 | base_tab | Tp 4.5M | T2 8.9M (~57 MB)
    float2* EC8    = (float2*)d_ws;
    int*    cnt    = (int*)(EC8 + N_EDGES);
    int*    cursor = cnt + N_ATOMS;
    int*    bsum   = cursor + N_ATOMS + 1;
    int*    boff   = bsum + SCAN_B;
    u32*    car    = (u32*)(boff + SCAN_B + 1);   // pad keeps recU 8B-aligned
    float2* recU   = (float2*)(car + N_ANGLES);
    float2* rec    = recU + N_ANGLES;
    u16*    WT1    = (u16*)(rec + N_ANGLES);
    u16*    WT2    = WT1 + 4096;
    u16*    WT3    = WT2 + 4096;
    float*  base_tab = (float*)(WT3 + 4096);
    u16*    Tp     = (u16*)(base_tab + 256*64);
    u32*    T2     = (u32*)(Tp + 2 * TSZ);

    fused_prep_kernel<<<E_BLK + P_BLK + Z_BLK, 256, 0, stream>>>(
        distances, sw, vec, edge_dst, species,
        W0, b0, W1, W2, W3, EC8, WT1, WT2, WT3, base_tab, cnt);
    angle_prep_kernel<<<(N_ANGLES + 255) / 256, 256, 0, stream>>>(
        a_src, a_dst, a_ca, EC8, cnt, car, recU);
    scanA_kernel<<<SCAN_B, 256, 0, stream>>>(cnt, bsum);
    scanB_kernel<<<1, 256, 0, stream>>>(bsum, boff);
    scanC_kernel<<<SCAN_B, 256, 0, stream>>>(cnt, boff, cursor);
    permute_kernel<<<(N_ANGLES + 255) / 256, 256, 0, stream>>>(
        recU, car, cursor, rec);
    build_kernel<<<136 * 2, 256, 0, stream>>>(
        W0, base_tab, WT1, WT2, WT3, b1, b2, b3, Tp);
    repack_kernel<<<(TSZ + 255) / 256, 256, 0, stream>>>(Tp, T2);
    lookup_kernel<<<(N_ATOMS + 3) / 4, 256, 0, stream>>>(rec, cursor, T2, out);
}

// Round 14
// 202.309 us; speedup vs baseline: 1.7924x; 1.0391x over previous
//
#include <hip/hip_runtime.h>

#define N_ATOMS   50000
#define N_EDGES   1600000
#define N_ANGLES  1500000
#define HALF_A    750000         // N_ANGLES/2
#define SCAN_B    196            // ceil(N_ATOMS/256)

// theta-table: theta = 8*sinh(u), u uniform on [-UMAX, UMAX], NT points.
#define NT      256
#define UMAX    4.852092f
#define H_U     0.038055623f     // 2*UMAX/(NT-1)
#define INV_HU  26.277306f       // (NT-1)/(2*UMAX)
#define TSZ     (136 * NT * 64)  // one partial table

#define E_BLK   6250             // edge range blocks
#define P_BLK   112              // prep range blocks (3*4096+16384)/256
#define Z_BLK   196              // cnt-zero range blocks

typedef unsigned short u16;
typedef unsigned int   u32;
typedef _Float16 f16x8 __attribute__((ext_vector_type(8)));
typedef float    f32x4 __attribute__((ext_vector_type(4)));
typedef u16      u16x8 __attribute__((ext_vector_type(8)));

__device__ __forceinline__ float silu_f(float x) {
    return __fdividef(x, 1.0f + __expf(-x));
}
__device__ __forceinline__ u16 f2h(float x) {
    _Float16 h = (_Float16)x;
    return __builtin_bit_cast(u16, h);
}
__device__ __forceinline__ float h2f(u16 u) {
    return (float)__builtin_bit_cast(_Float16, u);
}

// ---------------------------------------------------------------------------
// Fused prep: [0,E_BLK) edge records (species embedded in f16 LSBs);
// [E_BLK,+P_BLK) weight transpose + base_tab; [+P_BLK,+Z_BLK) cnt zeroing.
// ---------------------------------------------------------------------------
__global__ __launch_bounds__(256) void fused_prep_kernel(
    const float* __restrict__ distances, const float* __restrict__ sw,
    const float* __restrict__ vec, const int* __restrict__ edge_dst,
    const int* __restrict__ species,
    const float* __restrict__ W0, const float* __restrict__ b0,
    const float* __restrict__ W1, const float* __restrict__ W2,
    const float* __restrict__ W3,
    float2* __restrict__ EC8,
    u16* __restrict__ WT1, u16* __restrict__ WT2, u16* __restrict__ WT3,
    float* __restrict__ base_tab, int* __restrict__ cnt)
{
    const int bid = (int)blockIdx.x;
    const int tid = (int)threadIdx.x;

    if (bid < E_BLK) {
        int e = bid * 256 + tid;
        if (e >= N_EDGES) return;
        const float d   = distances[e];
        const float s   = sw[e];
        const float inv = 1.0f / d;
        const float sij = s * inv;
        const float c   = sij * inv;
        const int   sp  = species[edge_dst[e]];
        u16 h0 = f2h(sij);
        u16 h1 = f2h(c * vec[3*e+0]);
        u16 h2 = f2h(c * vec[3*e+1]);
        u16 h3 = f2h(c * vec[3*e+2]);
        h0 = (h0 & 0xFFFEu) | ((u16)( sp       & 1));
        h1 = (h1 & 0xFFFEu) | ((u16)((sp >> 1) & 1));
        h2 = (h2 & 0xFFFEu) | ((u16)((sp >> 2) & 1));
        h3 = (h3 & 0xFFFEu) | ((u16)((sp >> 3) & 1));
        const u32 lo = (u32)h0 | ((u32)h1 << 16);
        const u32 hi = (u32)h2 | ((u32)h3 << 16);
        EC8[e] = make_float2(__uint_as_float(lo), __uint_as_float(hi));
    } else if (bid < E_BLK + P_BLK) {
        int t = (bid - E_BLK) * 256 + tid;
        if (t < 3 * 4096) {
            int l = t >> 12, e = t & 4095, n = e >> 6, k = e & 63;
            const float* W = (l == 0) ? W1 : (l == 1) ? W2 : W3;
            u16* WT        = (l == 0) ? WT1 : (l == 1) ? WT2 : WT3;
            WT[n*64 + k] = f2h(W[k*64 + n]);
        }
        int u = t - 3 * 4096;
        if (u >= 0 && u < 256 * 64) {
            int sd = u >> 6, j = u & 63, s = sd >> 4, d = sd & 15;
            base_tab[u] = W0[(1+s)*64 + j] + W0[(17+d)*64 + j] + b0[j];
        }
    } else {
        int idx = (bid - E_BLK - P_BLK) * 256 + tid;
        if (idx < N_ATOMS) cnt[idx] = 0;
    }
}

// ---------------------------------------------------------------------------
// Per-angle record math (theta, pid, table coordinate) from two edge records.
// ---------------------------------------------------------------------------
__device__ __forceinline__ float2 make_rec(float2 Es, float2 Ed) {
    const u32 slo = __float_as_uint(Es.x), shi = __float_as_uint(Es.y);
    const u32 dlo = __float_as_uint(Ed.x), dhi = __float_as_uint(Ed.y);
    const int s1 = (int)((slo & 1u) | ((slo >> 15) & 2u)
                       | ((shi & 1u) << 2) | ((shi >> 13) & 8u));
    const int s2 = (int)((dlo & 1u) | ((dlo >> 15) & 2u)
                       | ((dhi & 1u) << 2) | ((dhi >> 13) & 8u));
    const float theta = h2f((u16)slo) * h2f((u16)dlo)
                      + h2f((u16)(slo >> 16)) * h2f((u16)(dlo >> 16))
                      + h2f((u16)shi) * h2f((u16)dhi)
                      + h2f((u16)(shi >> 16)) * h2f((u16)(dhi >> 16));
    const int s = min(s1, s2), d = max(s1, s2);
    const int pid = s*16 - (s*(s-1))/2 + (d - s);

    const float x  = theta * 0.125f;
    const float ax = fabsf(x);
    float uu = __logf(ax + __fsqrt_rn(fmaf(ax, ax, 1.0f)));
    uu = copysignf(uu, x);
    const float tt = fminf(fmaxf(fmaf(uu, INV_HU, UMAX * INV_HU), 0.0f),
                           (float)NT - 1.001f);
    const u32 tfx = (u32)(tt * 32768.0f);          // 15-bit fraction
    return make_float2(theta, __uint_as_float((tfx << 8) | (u32)pid));
}

// ---------------------------------------------------------------------------
// Fused angle prep, 2 angles/thread (i and i+HALF_A; both streams coalesced):
// 4 random EC8 gathers + 2 rank-atomics in flight per thread — doubles MLP
// vs R13. Writes unsorted records + (rank,ca) handles coalesced.
// ---------------------------------------------------------------------------
__global__ __launch_bounds__(256) void angle_prep_kernel(
    const int* __restrict__ a_src, const int* __restrict__ a_dst,
    const int* __restrict__ a_ca, const float2* __restrict__ EC8,
    int* __restrict__ cnt, u32* __restrict__ car, float2* __restrict__ recU)
{
    int i = (int)blockIdx.x * 256 + (int)threadIdx.x;
    if (i >= HALF_A) return;
    const int iA = i, iB = i + HALF_A;
    const int seA = a_src[iA], deA = a_dst[iA], caA = a_ca[iA];
    const int seB = a_src[iB], deB = a_dst[iB], caB = a_ca[iB];
    const float2 EsA = EC8[seA], EdA = EC8[deA];   // 4 random lines +
    const float2 EsB = EC8[seB], EdB = EC8[deB];   // 2 atomics all in flight
    const u32 rankA = (u32)atomicAdd(&cnt[caA], 1);
    const u32 rankB = (u32)atomicAdd(&cnt[caB], 1);

    car[iA]  = (rankA << 18) | (u32)caA;
    recU[iA] = make_rec(EsA, EdA);
    car[iB]  = (rankB << 18) | (u32)caB;
    recU[iB] = make_rec(EsB, EdB);
}

__global__ __launch_bounds__(256) void scanA_kernel(
    const int* __restrict__ cnt, int* __restrict__ bsum)
{
    __shared__ int ws[4];
    const int t = (int)threadIdx.x;
    const int idx = (int)blockIdx.x * 256 + t;
    int v = (idx < N_ATOMS) ? cnt[idx] : 0;
    #pragma unroll
    for (int off = 32; off; off >>= 1) v += __shfl_down(v, off, 64);
    if ((t & 63) == 0) ws[t >> 6] = v;
    __syncthreads();
    if (t == 0) bsum[blockIdx.x] = ws[0] + ws[1] + ws[2] + ws[3];
}

__global__ __launch_bounds__(256) void scanB_kernel(
    const int* __restrict__ bsum, int* __restrict__ boff)
{
    __shared__ int sh[256];
    const int t = (int)threadIdx.x;
    int v = (t < SCAN_B) ? bsum[t] : 0;
    sh[t] = v;
    __syncthreads();
    for (int off = 1; off < 256; off <<= 1) {
        int u = (t >= off) ? sh[t - off] : 0;
        __syncthreads();
        sh[t] += u;
        __syncthreads();
    }
    if (t < SCAN_B) boff[t] = sh[t] - v;   // exclusive
}

// cursor[a] = exclusive prefix (row START of atom a); sentinel cursor[N_ATOMS].
__global__ __launch_bounds__(256) void scanC_kernel(
    const int* __restrict__ cnt, const int* __restrict__ boff,
    int* __restrict__ cursor)
{
    __shared__ int sh[256];
    const int t = (int)threadIdx.x;
    const int idx = (int)blockIdx.x * 256 + t;
    int v = (idx < N_ATOMS) ? cnt[idx] : 0;
    sh[t] = v;
    __syncthreads();
    for (int off = 1; off < 256; off <<= 1) {
        int u = (t >= off) ? sh[t - off] : 0;
        __syncthreads();
        sh[t] += u;
        __syncthreads();
    }
    if (idx < N_ATOMS) {
        cursor[idx] = boff[blockIdx.x] + sh[t] - v;
        if (idx == N_ATOMS - 1) cursor[N_ATOMS] = boff[blockIdx.x] + sh[t];
    }
}

// ---------------------------------------------------------------------------
// Pure permutation: rec[cursor[ca]+rank] = recU[i]. Coalesced reads; the
// random 8B write granule is the irreducible cost of the sort.
// ---------------------------------------------------------------------------
__global__ __launch_bounds__(256) void permute_kernel(
    const float2* __restrict__ recU, const u32* __restrict__ car,
    const int* __restrict__ cursor, float2* __restrict__ rec)
{
    int i = (int)blockIdx.x * 256 + (int)threadIdx.x;
    if (i >= N_ANGLES) return;
    const u32 cr = car[i];
    const int ca   = (int)(cr & 0x3FFFFu);
    const int rank = (int)(cr >> 18);
    rec[cursor[ca] + rank] = recU[i];
}

// ---------------------------------------------------------------------------
// MFMA helpers (static indexing; LDS tile u16 index = row*64 + (col^((row&7)<<3)))
// ---------------------------------------------------------------------------
__device__ __forceinline__ void dense_mfma(const u16* __restrict__ strip,
    const u16* __restrict__ WT, int r15, int g4, f32x4 acc[4][4])
{
    #pragma unroll
    for (int kt = 0; kt < 2; ++kt) {
        f16x8 A[4], B[4];
        #pragma unroll
        for (int mt = 0; mt < 4; ++mt) {
            int row = mt*16 + r15;
            int col = (kt*32 + g4*8) ^ ((row & 7) << 3);
            A[mt] = *(const f16x8*)&strip[row*64 + col];
        }
        #pragma unroll
        for (int nt = 0; nt < 4; ++nt)
            B[nt] = *(const f16x8*)&WT[(nt*16 + r15)*64 + kt*32 + g4*8];
        #pragma unroll
        for (int mt = 0; mt < 4; ++mt) {
            #pragma unroll
            for (int nt = 0; nt < 4; ++nt)
                acc[mt][nt] = __builtin_amdgcn_mfma_f32_16x16x32_f16(
                    A[mt], B[nt], acc[mt][nt], 0, 0, 0);
        }
    }
}

__device__ __forceinline__ void act_store(u16* __restrict__ strip,
    const float* __restrict__ bias, int r15, int g4, f32x4 acc[4][4])
{
    float bn[4];
    #pragma unroll
    for (int nt = 0; nt < 4; ++nt) bn[nt] = bias[nt*16 + r15];
    #pragma unroll
    for (int mt = 0; mt < 4; ++mt) {
        #pragma unroll
        for (int r = 0; r < 4; ++r) {
            int row = mt*16 + g4*4 + r;
            int rsw = (row & 7) << 3;
            #pragma unroll
            for (int nt = 0; nt < 4; ++nt)
                strip[row*64 + ((nt*16 + r15) ^ rsw)] =
                    f2h(silu_f(acc[mt][nt][r] + bn[nt]));
        }
    }
}

// ---------------------------------------------------------------------------
// Table build: grid = 136 pairs x 2 m-passes. Partials summed in repack.
// ---------------------------------------------------------------------------
__global__ __launch_bounds__(256) void build_kernel(
    const float* __restrict__ W0, const float* __restrict__ base_tab,
    const u16* __restrict__ WT1, const u16* __restrict__ WT2,
    const u16* __restrict__ WT3,
    const float* __restrict__ b1, const float* __restrict__ b2,
    const float* __restrict__ b3,
    u16* __restrict__ Tp)
{
    __shared__ __align__(16) u16 act[256 * 64];   // 32 KB

    const int tid  = (int)threadIdx.x;
    const int lane = tid & 63;
    const int wv   = tid >> 6;
    const int r15  = lane & 15;
    const int g4   = lane >> 4;

    const int pid = (int)blockIdx.x >> 1;
    const int m   = (int)blockIdx.x & 1;
    // decode tri id -> (s, d), s <= d
    int s = 0, rem = pid;
    while (rem >= 16 - s) { rem -= 16 - s; ++s; }
    const int d = s + rem;

    const int idx = tid;                            // theta grid index
    const float u  = fmaf((float)idx, H_U, -UMAX);
    const float eu = __expf(u);
    const float theta = 4.0f * (eu - __frcp_rn(eu)); // 8*sinh(u)

    u16* strip = act + wv * 4096;

    f32x4 accG[4][4];
    #pragma unroll
    for (int nt = 0; nt < 4; ++nt) {
        float bv = b3[nt*16 + r15];                 // one b3 per partial
        #pragma unroll
        for (int mt = 0; mt < 4; ++mt) accG[mt][nt] = {bv, bv, bv, bv};
    }

    // layer 0 (one-hot collapsed)
    {
        const int p = m ? (d*16 + s) : (s*16 + d);
        const float4* bs4 = (const float4*)(base_tab + p*64);
        const float4* w04 = (const float4*)W0;
        const int rsw = (lane & 7) << 3;
        #pragma unroll
        for (int c = 0; c < 8; ++c) {
            float4 bl = bs4[2*c], bh = bs4[2*c+1];
            float4 wl = w04[2*c], wh = w04[2*c+1];
            u16x8 hv;
            hv[0] = f2h(silu_f(fmaf(theta, wl.x, bl.x)));
            hv[1] = f2h(silu_f(fmaf(theta, wl.y, bl.y)));
            hv[2] = f2h(silu_f(fmaf(theta, wl.z, bl.z)));
            hv[3] = f2h(silu_f(fmaf(theta, wl.w, bl.w)));
            hv[4] = f2h(silu_f(fmaf(theta, wh.x, bh.x)));
            hv[5] = f2h(silu_f(fmaf(theta, wh.y, bh.y)));
            hv[6] = f2h(silu_f(fmaf(theta, wh.z, bh.z)));
            hv[7] = f2h(silu_f(fmaf(theta, wh.w, bh.w)));
            *(u16x8*)&strip[lane*64 + ((c*8) ^ rsw)] = hv;
        }
    }
    // layer 1
    {
        f32x4 acc[4][4];
        #pragma unroll
        for (int mt = 0; mt < 4; ++mt)
            #pragma unroll
            for (int nt = 0; nt < 4; ++nt) acc[mt][nt] = {0.f,0.f,0.f,0.f};
        dense_mfma(strip, WT1, r15, g4, acc);
        act_store(strip, b1, r15, g4, acc);
    }
    // layer 2
    {
        f32x4 acc[4][4];
        #pragma unroll
        for (int mt = 0; mt < 4; ++mt)
            #pragma unroll
            for (int nt = 0; nt < 4; ++nt) acc[mt][nt] = {0.f,0.f,0.f,0.f};
        dense_mfma(strip, WT2, r15, g4, acc);
        act_store(strip, b2, r15, g4, acc);
    }
    // layer 3 -> accG
    dense_mfma(strip, WT3, r15, g4, accG);

    // stash partial G (f16) into act rows
    #pragma unroll
    for (int mt = 0; mt < 4; ++mt) {
        #pragma unroll
        for (int r = 0; r < 4; ++r) {
            int row = mt*16 + g4*4 + r;
            int rsw = (row & 7) << 3;
            #pragma unroll
            for (int nt = 0; nt < 4; ++nt)
                strip[row*64 + ((nt*16 + r15) ^ rsw)] = f2h(accG[mt][nt][r]);
        }
    }
    __syncthreads();

    // coalesced copy-out: thread tid owns act row tid -> Tp[m][pid][idx]
    u16* dst = Tp + (size_t)m * TSZ + ((size_t)pid * NT + (size_t)idx) * 64;
    const int rsw = (tid & 7) << 3;
    #pragma unroll
    for (int c = 0; c < 8; ++c)
        *(u16x8*)(dst + c*8) = *(const u16x8*)&act[tid*64 + ((c*8) ^ rsw)];
}

// ---------------------------------------------------------------------------
// Repack: sum the two m-partials and pair-pack rows i, i+1.
// ---------------------------------------------------------------------------
__global__ __launch_bounds__(256) void repack_kernel(
    const u16* __restrict__ Tp, u32* __restrict__ T2)
{
    int idx = (int)blockIdx.x * 256 + (int)threadIdx.x;
    if (idx >= TSZ) return;
    const int row = (idx >> 6) & (NT - 1);
    const int nxt = (row < NT - 1) ? idx + 64 : idx;
    const float ga = h2f(Tp[idx]) + h2f(Tp[TSZ + idx]);
    const float gb = h2f(Tp[nxt]) + h2f(Tp[TSZ + nxt]);
    T2[idx] = (u32)f2h(ga) | ((u32)f2h(gb) << 16);
}

// ---------------------------------------------------------------------------
// Lookup: wave-per-atom CSR walk, lane = feature. Records for the whole
// segment are fetched by ONE cooperative coalesced vector load (lane l ->
// rec[base+l], 64 angles/instr) and broadcast via __shfl — no per-iteration
// scalar-load chain. UNROLL x4: 4 independent T2 loads in flight.
// ---------------------------------------------------------------------------
__global__ __launch_bounds__(256) void lookup_kernel(
    const float2* __restrict__ rec, const int* __restrict__ cursor,
    const u32* __restrict__ T2, float* __restrict__ out)
{
    const int tid  = (int)threadIdx.x;
    const int lane = tid & 63;
    const int wv   = tid >> 6;
    const int atom = (int)blockIdx.x * 4 + wv;
    if (atom >= N_ATOMS) return;

    const int start = cursor[atom];
    const int end   = cursor[atom + 1];

    float acc0 = 0.f, acc1 = 0.f, acc2 = 0.f, acc3 = 0.f;
    for (int base = start; base < end; base += 64) {
        const int len = min(64, end - base);
        const float2 rv = rec[base + min(lane, len - 1)];   // cooperative
        const float thp = rv.x;
        const int   wp  = (int)__float_as_uint(rv.y);

        int j = 0;
        for (; j + 3 < len; j += 4) {
            const float th0 = __shfl(thp, j),     th1 = __shfl(thp, j + 1);
            const float th2 = __shfl(thp, j + 2), th3 = __shfl(thp, j + 3);
            const u32 w0 = (u32)__shfl(wp, j),     w1 = (u32)__shfl(wp, j + 1);
            const u32 w2 = (u32)__shfl(wp, j + 2), w3 = (u32)__shfl(wp, j + 3);
            const u32 pr0 = T2[((w0 & 255u) << 14) + ((w0 >> 23) << 6) + (u32)lane];
            const u32 pr1 = T2[((w1 & 255u) << 14) + ((w1 >> 23) << 6) + (u32)lane];
            const u32 pr2 = T2[((w2 & 255u) << 14) + ((w2 >> 23) << 6) + (u32)lane];
            const u32 pr3 = T2[((w3 & 255u) << 14) + ((w3 >> 23) << 6) + (u32)lane];
            const float fr0 = (float)((w0 >> 8) & 32767u) * (1.0f / 32768.0f);
            const float fr1 = (float)((w1 >> 8) & 32767u) * (1.0f / 32768.0f);
            const float fr2 = (float)((w2 >> 8) & 32767u) * (1.0f / 32768.0f);
            const float fr3 = (float)((w3 >> 8) & 32767u) * (1.0f / 32768.0f);
            float ga, gb;
            ga = h2f((u16)(pr0 & 0xFFFFu)); gb = h2f((u16)(pr0 >> 16));
            acc0 = fmaf(fmaf(fr0, gb - ga, ga), th0, acc0);
            ga = h2f((u16)(pr1 & 0xFFFFu)); gb = h2f((u16)(pr1 >> 16));
            acc1 = fmaf(fmaf(fr1, gb - ga, ga), th1, acc1);
            ga = h2f((u16)(pr2 & 0xFFFFu)); gb = h2f((u16)(pr2 >> 16));
            acc2 = fmaf(fmaf(fr2, gb - ga, ga), th2, acc2);
            ga = h2f((u16)(pr3 & 0xFFFFu)); gb = h2f((u16)(pr3 >> 16));
            acc3 = fmaf(fmaf(fr3, gb - ga, ga), th3, acc3);
        }
        for (; j < len; ++j) {
            const float th = __shfl(thp, j);
            const u32 w  = (u32)__shfl(wp, j);
            const u32 pr = T2[((w & 255u) << 14) + ((w >> 23) << 6) + (u32)lane];
            const float fr = (float)((w >> 8) & 32767u) * (1.0f / 32768.0f);
            const float ga = h2f((u16)(pr & 0xFFFFu));
            const float gb = h2f((u16)(pr >> 16));
            acc0 = fmaf(fmaf(fr, gb - ga, ga), th, acc0);
        }
    }
    out[(size_t)atom * 64 + lane] = (acc0 + acc1) + (acc2 + acc3);
}

extern "C" void kernel_launch(void* const* d_in, const int* in_sizes, int n_in,
                              void* d_out, int out_size, void* d_ws, size_t ws_size,
                              hipStream_t stream) {
    const int*   species   = (const int*)  d_in[0];
    const int*   edge_dst  = (const int*)  d_in[1];
    const float* distances = (const float*)d_in[2];
    const float* sw        = (const float*)d_in[3];
    const float* vec       = (const float*)d_in[4];
    const int*   a_src     = (const int*)  d_in[5];
    const int*   a_dst     = (const int*)  d_in[6];
    const int*   a_ca      = (const int*)  d_in[7];
    const float* W0 = (const float*)d_in[8];
    const float* b0 = (const float*)d_in[9];
    const float* W1 = (const float*)d_in[10];
    const float* b1 = (const float*)d_in[11];
    const float* W2 = (const float*)d_in[12];
    const float* b2 = (const float*)d_in[13];
    const float* W3 = (const float*)d_in[14];
    const float* b3 = (const float*)d_in[15];
    float* out = (float*)d_out;

    // ws: EC8 12.8M | cnt | cursor(+1) | bsum | boff(+pad) | car 6M |
    //     recU 12M | rec 12M | WT1/2/3 | base_tab | Tp 4.5M | T2 8.9M (~57 MB)
    float2* EC8    = (float2*)d_ws;
    int*    cnt    = (int*)(EC8 + N_EDGES);
    int*    cursor = cnt + N_ATOMS;
    int*    bsum   = cursor + N_ATOMS + 1;
    int*    boff   = bsum + SCAN_B;
    u32*    car    = (u32*)(boff + SCAN_B + 1);   // pad keeps recU 8B-aligned
    float2* recU   = (float2*)(car + N_ANGLES);
    float2* rec    = recU + N_ANGLES;
    u16*    WT1    = (u16*)(rec + N_ANGLES);
    u16*    WT2    = WT1 + 4096;
    u16*    WT3    = WT2 + 4096;
    float*  base_tab = (float*)(WT3 + 4096);
    u16*    Tp     = (u16*)(base_tab + 256*64);
    u32*    T2     = (u32*)(Tp + 2 * TSZ);

    fused_prep_kernel<<<E_BLK + P_BLK + Z_BLK, 256, 0, stream>>>(
        distances, sw, vec, edge_dst, species,
        W0, b0, W1, W2, W3, EC8, WT1, WT2, WT3, base_tab, cnt);
    angle_prep_kernel<<<(HALF_A + 255) / 256, 256, 0, stream>>>(
        a_src, a_dst, a_ca, EC8, cnt, car, recU);
    scanA_kernel<<<SCAN_B, 256, 0, stream>>>(cnt, bsum);
    scanB_kernel<<<1, 256, 0, stream>>>(bsum, boff);
    scanC_kernel<<<SCAN_B, 256, 0, stream>>>(cnt, boff, cursor);
    permute_kernel<<<(N_ANGLES + 255) / 256, 256, 0, stream>>>(
        recU, car, cursor, rec);
    build_kernel<<<136 * 2, 256, 0, stream>>>(
        W0, base_tab, WT1, WT2, WT3, b1, b2, b3, Tp);
    repack_kernel<<<(TSZ + 255) / 256, 256, 0, stream>>>(Tp, T2);
    lookup_kernel<<<(N_ATOMS + 3) / 4, 256, 0, stream>>>(rec, cursor, T2, out);
}

// Round 15
// 199.233 us; speedup vs baseline: 1.8200x; 1.0154x over previous
//
#include <hip/hip_runtime.h>

#define N_ATOMS   50000
#define N_EDGES   1600000
#define N_ANGLES  1500000
#define SCAN_B    196            // ceil(N_ATOMS/256)

// theta-table: theta = 8*sinh(u), u uniform on [-UMAX, UMAX], NT points.
#define NT      256
#define UMAX    4.852092f
#define H_U     0.038055623f     // 2*UMAX/(NT-1)
#define INV_HU  26.277306f       // (NT-1)/(2*UMAX)
#define TSZ     (136 * NT * 64)  // one partial table

#define E_BLK   6250             // edge range blocks
#define P_BLK   112              // prep range blocks (3*4096+16384)/256
#define Z_BLK   196              // cnt-zero range blocks

typedef unsigned short u16;
typedef unsigned int   u32;
typedef _Float16 f16x8 __attribute__((ext_vector_type(8)));
typedef float    f32x4 __attribute__((ext_vector_type(4)));
typedef u16      u16x8 __attribute__((ext_vector_type(8)));

__device__ __forceinline__ float silu_f(float x) {
    return __fdividef(x, 1.0f + __expf(-x));
}
__device__ __forceinline__ u16 f2h(float x) {
    _Float16 h = (_Float16)x;
    return __builtin_bit_cast(u16, h);
}
__device__ __forceinline__ float h2f(u16 u) {
    return (float)__builtin_bit_cast(_Float16, u);
}

// ---------------------------------------------------------------------------
// Fused prep: [0,E_BLK) edge records (species embedded in f16 LSBs);
// [E_BLK,+P_BLK) weight transpose + base_tab; [+P_BLK,+Z_BLK) cnt zeroing.
// ---------------------------------------------------------------------------
__global__ __launch_bounds__(256) void fused_prep_kernel(
    const float* __restrict__ distances, const float* __restrict__ sw,
    const float* __restrict__ vec, const int* __restrict__ edge_dst,
    const int* __restrict__ species,
    const float* __restrict__ W0, const float* __restrict__ b0,
    const float* __restrict__ W1, const float* __restrict__ W2,
    const float* __restrict__ W3,
    float2* __restrict__ EC8,
    u16* __restrict__ WT1, u16* __restrict__ WT2, u16* __restrict__ WT3,
    float* __restrict__ base_tab, int* __restrict__ cnt)
{
    const int bid = (int)blockIdx.x;
    const int tid = (int)threadIdx.x;

    if (bid < E_BLK) {
        int e = bid * 256 + tid;
        if (e >= N_EDGES) return;
        const float d   = distances[e];
        const float s   = sw[e];
        const float inv = 1.0f / d;
        const float sij = s * inv;
        const float c   = sij * inv;
        const int   sp  = species[edge_dst[e]];
        u16 h0 = f2h(sij);
        u16 h1 = f2h(c * vec[3*e+0]);
        u16 h2 = f2h(c * vec[3*e+1]);
        u16 h3 = f2h(c * vec[3*e+2]);
        h0 = (h0 & 0xFFFEu) | ((u16)( sp       & 1));
        h1 = (h1 & 0xFFFEu) | ((u16)((sp >> 1) & 1));
        h2 = (h2 & 0xFFFEu) | ((u16)((sp >> 2) & 1));
        h3 = (h3 & 0xFFFEu) | ((u16)((sp >> 3) & 1));
        const u32 lo = (u32)h0 | ((u32)h1 << 16);
        const u32 hi = (u32)h2 | ((u32)h3 << 16);
        EC8[e] = make_float2(__uint_as_float(lo), __uint_as_float(hi));
    } else if (bid < E_BLK + P_BLK) {
        int t = (bid - E_BLK) * 256 + tid;
        if (t < 3 * 4096) {
            int l = t >> 12, e = t & 4095, n = e >> 6, k = e & 63;
            const float* W = (l == 0) ? W1 : (l == 1) ? W2 : W3;
            u16* WT        = (l == 0) ? WT1 : (l == 1) ? WT2 : WT3;
            WT[n*64 + k] = f2h(W[k*64 + n]);
        }
        int u = t - 3 * 4096;
        if (u >= 0 && u < 256 * 64) {
            int sd = u >> 6, j = u & 63, s = sd >> 4, d = sd & 15;
            base_tab[u] = W0[(1+s)*64 + j] + W0[(17+d)*64 + j] + b0[j];
        }
    } else {
        int idx = (bid - E_BLK - P_BLK) * 256 + tid;
        if (idx < N_ATOMS) cnt[idx] = 0;
    }
}

// ---------------------------------------------------------------------------
// Per-angle 4B record: (tfx<<8)|pid — theta itself is NOT stored; the table
// coordinate's 15-bit fraction encodes it to ~1e-6 relative, and the H-table
// (= G*theta) makes lookup theta-free.
// ---------------------------------------------------------------------------
__device__ __forceinline__ u32 make_rec(float2 Es, float2 Ed) {
    const u32 slo = __float_as_uint(Es.x), shi = __float_as_uint(Es.y);
    const u32 dlo = __float_as_uint(Ed.x), dhi = __float_as_uint(Ed.y);
    const int s1 = (int)((slo & 1u) | ((slo >> 15) & 2u)
                       | ((shi & 1u) << 2) | ((shi >> 13) & 8u));
    const int s2 = (int)((dlo & 1u) | ((dlo >> 15) & 2u)
                       | ((dhi & 1u) << 2) | ((dhi >> 13) & 8u));
    const float theta = h2f((u16)slo) * h2f((u16)dlo)
                      + h2f((u16)(slo >> 16)) * h2f((u16)(dlo >> 16))
                      + h2f((u16)shi) * h2f((u16)dhi)
                      + h2f((u16)(shi >> 16)) * h2f((u16)(dhi >> 16));
    const int s = min(s1, s2), d = max(s1, s2);
    const int pid = s*16 - (s*(s-1))/2 + (d - s);

    const float x  = theta * 0.125f;
    const float ax = fabsf(x);
    float uu = __logf(ax + __fsqrt_rn(fmaf(ax, ax, 1.0f)));
    uu = copysignf(uu, x);
    const float tt = fminf(fmaxf(fmaf(uu, INV_HU, UMAX * INV_HU), 0.0f),
                           (float)NT - 1.001f);
    const u32 tfx = (u32)(tt * 32768.0f);          // 15-bit fraction
    return (tfx << 8) | (u32)pid;
}

// ---------------------------------------------------------------------------
// Fused angle prep (1 angle/thread — R14's x2 proved the kernel is at the
// random-gather BW ceiling; occupancy matters more than per-thread MLP):
// rank-atomic overlaps the 2 EC8 gathers; coalesced recU/car writes.
// ---------------------------------------------------------------------------
__global__ __launch_bounds__(256) void angle_prep_kernel(
    const int* __restrict__ a_src, const int* __restrict__ a_dst,
    const int* __restrict__ a_ca, const float2* __restrict__ EC8,
    int* __restrict__ cnt, u32* __restrict__ car, u32* __restrict__ recU)
{
    int i = (int)blockIdx.x * 256 + (int)threadIdx.x;
    if (i >= N_ANGLES) return;
    const int se = a_src[i], de = a_dst[i], ca = a_ca[i];
    const float2 Es = EC8[se], Ed = EC8[de];   // 2 random lines in flight
    const u32 rank = (u32)atomicAdd(&cnt[ca], 1);
    car[i]  = (rank << 18) | (u32)ca;
    recU[i] = make_rec(Es, Ed);
}

__global__ __launch_bounds__(256) void scanA_kernel(
    const int* __restrict__ cnt, int* __restrict__ bsum)
{
    __shared__ int ws[4];
    const int t = (int)threadIdx.x;
    const int idx = (int)blockIdx.x * 256 + t;
    int v = (idx < N_ATOMS) ? cnt[idx] : 0;
    #pragma unroll
    for (int off = 32; off; off >>= 1) v += __shfl_down(v, off, 64);
    if ((t & 63) == 0) ws[t >> 6] = v;
    __syncthreads();
    if (t == 0) bsum[blockIdx.x] = ws[0] + ws[1] + ws[2] + ws[3];
}

__global__ __launch_bounds__(256) void scanB_kernel(
    const int* __restrict__ bsum, int* __restrict__ boff)
{
    __shared__ int sh[256];
    const int t = (int)threadIdx.x;
    int v = (t < SCAN_B) ? bsum[t] : 0;
    sh[t] = v;
    __syncthreads();
    for (int off = 1; off < 256; off <<= 1) {
        int u = (t >= off) ? sh[t - off] : 0;
        __syncthreads();
        sh[t] += u;
        __syncthreads();
    }
    if (t < SCAN_B) boff[t] = sh[t] - v;   // exclusive
}

// cursor[a] = exclusive prefix (row START of atom a); sentinel cursor[N_ATOMS].
__global__ __launch_bounds__(256) void scanC_kernel(
    const int* __restrict__ cnt, const int* __restrict__ boff,
    int* __restrict__ cursor)
{
    __shared__ int sh[256];
    const int t = (int)threadIdx.x;
    const int idx = (int)blockIdx.x * 256 + t;
    int v = (idx < N_ATOMS) ? cnt[idx] : 0;
    sh[t] = v;
    __syncthreads();
    for (int off = 1; off < 256; off <<= 1) {
        int u = (t >= off) ? sh[t - off] : 0;
        __syncthreads();
        sh[t] += u;
        __syncthreads();
    }
    if (idx < N_ATOMS) {
        cursor[idx] = boff[blockIdx.x] + sh[t] - v;
        if (idx == N_ATOMS - 1) cursor[N_ATOMS] = boff[blockIdx.x] + sh[t];
    }
}

// ---------------------------------------------------------------------------
// Pure permutation of 4B records: rec[cursor[ca]+rank] = recU[i].
// 8 records per 32B write sector (was 4 at 8B) -> half the granule traffic.
// ---------------------------------------------------------------------------
__global__ __launch_bounds__(256) void permute_kernel(
    const u32* __restrict__ recU, const u32* __restrict__ car,
    const int* __restrict__ cursor, u32* __restrict__ rec)
{
    int i = (int)blockIdx.x * 256 + (int)threadIdx.x;
    if (i >= N_ANGLES) return;
    const u32 cr = car[i];
    const int ca   = (int)(cr & 0x3FFFFu);
    const int rank = (int)(cr >> 18);
    rec[cursor[ca] + rank] = recU[i];
}

// ---------------------------------------------------------------------------
// MFMA helpers (static indexing; LDS tile u16 index = row*64 + (col^((row&7)<<3)))
// ---------------------------------------------------------------------------
__device__ __forceinline__ void dense_mfma(const u16* __restrict__ strip,
    const u16* __restrict__ WT, int r15, int g4, f32x4 acc[4][4])
{
    #pragma unroll
    for (int kt = 0; kt < 2; ++kt) {
        f16x8 A[4], B[4];
        #pragma unroll
        for (int mt = 0; mt < 4; ++mt) {
            int row = mt*16 + r15;
            int col = (kt*32 + g4*8) ^ ((row & 7) << 3);
            A[mt] = *(const f16x8*)&strip[row*64 + col];
        }
        #pragma unroll
        for (int nt = 0; nt < 4; ++nt)
            B[nt] = *(const f16x8*)&WT[(nt*16 + r15)*64 + kt*32 + g4*8];
        #pragma unroll
        for (int mt = 0; mt < 4; ++mt) {
            #pragma unroll
            for (int nt = 0; nt < 4; ++nt)
                acc[mt][nt] = __builtin_amdgcn_mfma_f32_16x16x32_f16(
                    A[mt], B[nt], acc[mt][nt], 0, 0, 0);
        }
    }
}

__device__ __forceinline__ void act_store(u16* __restrict__ strip,
    const float* __restrict__ bias, int r15, int g4, f32x4 acc[4][4])
{
    float bn[4];
    #pragma unroll
    for (int nt = 0; nt < 4; ++nt) bn[nt] = bias[nt*16 + r15];
    #pragma unroll
    for (int mt = 0; mt < 4; ++mt) {
        #pragma unroll
        for (int r = 0; r < 4; ++r) {
            int row = mt*16 + g4*4 + r;
            int rsw = (row & 7) << 3;
            #pragma unroll
            for (int nt = 0; nt < 4; ++nt)
                strip[row*64 + ((nt*16 + r15) ^ rsw)] =
                    f2h(silu_f(acc[mt][nt][r] + bn[nt]));
        }
    }
}

// ---------------------------------------------------------------------------
// Table build: grid = 136 pairs x 2 m-passes. Partials (G, not G*theta)
// stored f16; repack sums and multiplies by theta.
// ---------------------------------------------------------------------------
__global__ __launch_bounds__(256) void build_kernel(
    const float* __restrict__ W0, const float* __restrict__ base_tab,
    const u16* __restrict__ WT1, const u16* __restrict__ WT2,
    const u16* __restrict__ WT3,
    const float* __restrict__ b1, const float* __restrict__ b2,
    const float* __restrict__ b3,
    u16* __restrict__ Tp)
{
    __shared__ __align__(16) u16 act[256 * 64];   // 32 KB

    const int tid  = (int)threadIdx.x;
    const int lane = tid & 63;
    const int wv   = tid >> 6;
    const int r15  = lane & 15;
    const int g4   = lane >> 4;

    const int pid = (int)blockIdx.x >> 1;
    const int m   = (int)blockIdx.x & 1;
    // decode tri id -> (s, d), s <= d
    int s = 0, rem = pid;
    while (rem >= 16 - s) { rem -= 16 - s; ++s; }
    const int d = s + rem;

    const int idx = tid;                            // theta grid index
    const float u  = fmaf((float)idx, H_U, -UMAX);
    const float eu = __expf(u);
    const float theta = 4.0f * (eu - __frcp_rn(eu)); // 8*sinh(u)

    u16* strip = act + wv * 4096;

    f32x4 accG[4][4];
    #pragma unroll
    for (int nt = 0; nt < 4; ++nt) {
        float bv = b3[nt*16 + r15];                 // one b3 per partial
        #pragma unroll
        for (int mt = 0; mt < 4; ++mt) accG[mt][nt] = {bv, bv, bv, bv};
    }

    // layer 0 (one-hot collapsed)
    {
        const int p = m ? (d*16 + s) : (s*16 + d);
        const float4* bs4 = (const float4*)(base_tab + p*64);
        const float4* w04 = (const float4*)W0;
        const int rsw = (lane & 7) << 3;
        #pragma unroll
        for (int c = 0; c < 8; ++c) {
            float4 bl = bs4[2*c], bh = bs4[2*c+1];
            float4 wl = w04[2*c], wh = w04[2*c+1];
            u16x8 hv;
            hv[0] = f2h(silu_f(fmaf(theta, wl.x, bl.x)));
            hv[1] = f2h(silu_f(fmaf(theta, wl.y, bl.y)));
            hv[2] = f2h(silu_f(fmaf(theta, wl.z, bl.z)));
            hv[3] = f2h(silu_f(fmaf(theta, wl.w, bl.w)));
            hv[4] = f2h(silu_f(fmaf(theta, wh.x, bh.x)));
            hv[5] = f2h(silu_f(fmaf(theta, wh.y, bh.y)));
            hv[6] = f2h(silu_f(fmaf(theta, wh.z, bh.z)));
            hv[7] = f2h(silu_f(fmaf(theta, wh.w, bh.w)));
            *(u16x8*)&strip[lane*64 + ((c*8) ^ rsw)] = hv;
        }
    }
    // layer 1
    {
        f32x4 acc[4][4];
        #pragma unroll
        for (int mt = 0; mt < 4; ++mt)
            #pragma unroll
            for (int nt = 0; nt < 4; ++nt) acc[mt][nt] = {0.f,0.f,0.f,0.f};
        dense_mfma(strip, WT1, r15, g4, acc);
        act_store(strip, b1, r15, g4, acc);
    }
    // layer 2
    {
        f32x4 acc[4][4];
        #pragma unroll
        for (int mt = 0; mt < 4; ++mt)
            #pragma unroll
            for (int nt = 0; nt < 4; ++nt) acc[mt][nt] = {0.f,0.f,0.f,0.f};
        dense_mfma(strip, WT2, r15, g4, acc);
        act_store(strip, b2, r15, g4, acc);
    }
    // layer 3 -> accG
    dense_mfma(strip, WT3, r15, g4, accG);

    // stash partial G (f16) into act rows
    #pragma unroll
    for (int mt = 0; mt < 4; ++mt) {
        #pragma unroll
        for (int r = 0; r < 4; ++r) {
            int row = mt*16 + g4*4 + r;
            int rsw = (row & 7) << 3;
            #pragma unroll
            for (int nt = 0; nt < 4; ++nt)
                strip[row*64 + ((nt*16 + r15) ^ rsw)] = f2h(accG[mt][nt][r]);
        }
    }
    __syncthreads();

    // coalesced copy-out: thread tid owns act row tid -> Tp[m][pid][idx]
    u16* dst = Tp + (size_t)m * TSZ + ((size_t)pid * NT + (size_t)idx) * 64;
    const int rsw = (tid & 7) << 3;
    #pragma unroll
    for (int c = 0; c < 8; ++c)
        *(u16x8*)(dst + c*8) = *(const u16x8*)&act[tid*64 + ((c*8) ^ rsw)];
}

// ---------------------------------------------------------------------------
// Repack: H-table. H(row) = (G_m0 + G_m1)(theta(row)) * theta(row), pair-
// packed rows (i, i+1) as 2xf16 in one u32 -> lookup is theta-free.
// ---------------------------------------------------------------------------
__global__ __launch_bounds__(256) void repack_kernel(
    const u16* __restrict__ Tp, u32* __restrict__ T2)
{
    int idx = (int)blockIdx.x * 256 + (int)threadIdx.x;
    if (idx >= TSZ) return;
    const int row = (idx >> 6) & (NT - 1);
    const int nxt = (row < NT - 1) ? idx + 64 : idx;
    const int rown = (row < NT - 1) ? row + 1 : row;

    const float ua  = fmaf((float)row,  H_U, -UMAX);
    const float ub  = fmaf((float)rown, H_U, -UMAX);
    const float ea  = __expf(ua), eb = __expf(ub);
    const float tha = 4.0f * (ea - __frcp_rn(ea));
    const float thb = 4.0f * (eb - __frcp_rn(eb));

    const float ha = (h2f(Tp[idx]) + h2f(Tp[TSZ + idx])) * tha;
    const float hb = (h2f(Tp[nxt]) + h2f(Tp[TSZ + nxt])) * thb;
    T2[idx] = (u32)f2h(ha) | ((u32)f2h(hb) << 16);
}

// ---------------------------------------------------------------------------
// Lookup: wave-per-atom CSR walk, lane = feature. 4B records fetched by ONE
// cooperative coalesced load per 64 angles, broadcast via a single __shfl;
// H-table -> acc += lerp only (no theta). UNROLL x4 for MLP.
// ---------------------------------------------------------------------------
__global__ __launch_bounds__(256) void lookup_kernel(
    const u32* __restrict__ rec, const int* __restrict__ cursor,
    const u32* __restrict__ T2, float* __restrict__ out)
{
    const int tid  = (int)threadIdx.x;
    const int lane = tid & 63;
    const int wv   = tid >> 6;
    const int atom = (int)blockIdx.x * 4 + wv;
    if (atom >= N_ATOMS) return;

    const int start = cursor[atom];
    const int end   = cursor[atom + 1];

    float acc0 = 0.f, acc1 = 0.f, acc2 = 0.f, acc3 = 0.f;
    for (int base = start; base < end; base += 64) {
        const int len = min(64, end - base);
        const int wp  = (int)rec[base + min(lane, len - 1)];   // cooperative

        int j = 0;
        for (; j + 3 < len; j += 4) {
            const u32 w0 = (u32)__shfl(wp, j),     w1 = (u32)__shfl(wp, j + 1);
            const u32 w2 = (u32)__shfl(wp, j + 2), w3 = (u32)__shfl(wp, j + 3);
            const u32 pr0 = T2[((w0 & 255u) << 14) + ((w0 >> 23) << 6) + (u32)lane];
            const u32 pr1 = T2[((w1 & 255u) << 14) + ((w1 >> 23) << 6) + (u32)lane];
            const u32 pr2 = T2[((w2 & 255u) << 14) + ((w2 >> 23) << 6) + (u32)lane];
            const u32 pr3 = T2[((w3 & 255u) << 14) + ((w3 >> 23) << 6) + (u32)lane];
            const float fr0 = (float)((w0 >> 8) & 32767u) * (1.0f / 32768.0f);
            const float fr1 = (float)((w1 >> 8) & 32767u) * (1.0f / 32768.0f);
            const float fr2 = (float)((w2 >> 8) & 32767u) * (1.0f / 32768.0f);
            const float fr3 = (float)((w3 >> 8) & 32767u) * (1.0f / 32768.0f);
            float ga, gb;
            ga = h2f((u16)(pr0 & 0xFFFFu)); gb = h2f((u16)(pr0 >> 16));
            acc0 += fmaf(fr0, gb - ga, ga);
            ga = h2f((u16)(pr1 & 0xFFFFu)); gb = h2f((u16)(pr1 >> 16));
            acc1 += fmaf(fr1, gb - ga, ga);
            ga = h2f((u16)(pr2 & 0xFFFFu)); gb = h2f((u16)(pr2 >> 16));
            acc2 += fmaf(fr2, gb - ga, ga);
            ga = h2f((u16)(pr3 & 0xFFFFu)); gb = h2f((u16)(pr3 >> 16));
            acc3 += fmaf(fr3, gb - ga, ga);
        }
        for (; j < len; ++j) {
            const u32 w  = (u32)__shfl(wp, j);
            const u32 pr = T2[((w & 255u) << 14) + ((w >> 23) << 6) + (u32)lane];
            const float fr = (float)((w >> 8) & 32767u) * (1.0f / 32768.0f);
            const float ga = h2f((u16)(pr & 0xFFFFu));
            const float gb = h2f((u16)(pr >> 16));
            acc0 += fmaf(fr, gb - ga, ga);
        }
    }
    out[(size_t)atom * 64 + lane] = (acc0 + acc1) + (acc2 + acc3);
}

extern "C" void kernel_launch(void* const* d_in, const int* in_sizes, int n_in,
                              void* d_out, int out_size, void* d_ws, size_t ws_size,
                              hipStream_t stream) {
    const int*   species   = (const int*)  d_in[0];
    const int*   edge_dst  = (const int*)  d_in[1];
    const float* distances = (const float*)d_in[2];
    const float* sw        = (const float*)d_in[3];
    const float* vec       = (const float*)d_in[4];
    const int*   a_src     = (const int*)  d_in[5];
    const int*   a_dst     = (const int*)  d_in[6];
    const int*   a_ca      = (const int*)  d_in[7];
    const float* W0 = (const float*)d_in[8];
    const float* b0 = (const float*)d_in[9];
    const float* W1 = (const float*)d_in[10];
    const float* b1 = (const float*)d_in[11];
    const float* W2 = (const float*)d_in[12];
    const float* b2 = (const float*)d_in[13];
    const float* W3 = (const float*)d_in[14];
    const float* b3 = (const float*)d_in[15];
    float* out = (float*)d_out;

    // ws: EC8 12.8M | cnt | cursor(+1) | bsum | boff(+pad) | car 6M |
    //     recU 6M | rec 6M | WT1/2/3 | base_tab | Tp 4.5M | T2 8.9M (~45 MB)
    float2* EC8    = (float2*)d_ws;
    int*    cnt    = (int*)(EC8 + N_EDGES);
    int*    cursor = cnt + N_ATOMS;
    int*    bsum   = cursor + N_ATOMS + 1;
    int*    boff   = bsum + SCAN_B;
    u32*    car    = (u32*)(boff + SCAN_B + 1);
    u32*    recU   = car + N_ANGLES;
    u32*    rec    = recU + N_ANGLES;
    u16*    WT1    = (u16*)(rec + N_ANGLES);
    u16*    WT2    = WT1 + 4096;
    u16*    WT3    = WT2 + 4096;
    float*  base_tab = (float*)(WT3 + 4096);
    u16*    Tp     = (u16*)(base_tab + 256*64);
    u32*    T2     = (u32*)(Tp + 2 * TSZ);

    fused_prep_kernel<<<E_BLK + P_BLK + Z_BLK, 256, 0, stream>>>(
        distances, sw, vec, edge_dst, species,
        W0, b0, W1, W2, W3, EC8, WT1, WT2, WT3, base_tab, cnt);
    angle_prep_kernel<<<(N_ANGLES + 255) / 256, 256, 0, stream>>>(
        a_src, a_dst, a_ca, EC8, cnt, car, recU);
    scanA_kernel<<<SCAN_B, 256, 0, stream>>>(cnt, bsum);
    scanB_kernel<<<1, 256, 0, stream>>>(bsum, boff);
    scanC_kernel<<<SCAN_B, 256, 0, stream>>>(cnt, boff, cursor);
    permute_kernel<<<(N_ANGLES + 255) / 256, 256, 0, stream>>>(
        recU, car, cursor, rec);
    build_kernel<<<136 * 2, 256, 0, stream>>>(
        W0, base_tab, WT1, WT2, WT3, b1, b2, b3, Tp);
    repack_kernel<<<(TSZ + 255) / 256, 256, 0, stream>>>(Tp, T2);
    lookup_kernel<<<(N_ATOMS + 3) / 4, 256, 0, stream>>>(rec, cursor, T2, out);
}